// Round 1
// baseline (649.070 us; speedup 1.0000x reference)
//
#include <hip/hip_runtime.h>
#include <type_traits>

#define BATCH 2
#define S_LEN 2048
#define DIM 2048
#define NH 16
#define NKV 4
#define HD 128

typedef _Float16 f16x8 __attribute__((ext_vector_type(8)));
typedef float f32x4 __attribute__((ext_vector_type(4)));
typedef unsigned int u32x4 __attribute__((ext_vector_type(4)));
typedef unsigned short u16x4 __attribute__((ext_vector_type(4)));
typedef unsigned short u16x8 __attribute__((ext_vector_type(8)));

__device__ __forceinline__ unsigned short f2h_bits(float f) {
  _Float16 h = (_Float16)f;
  return __builtin_bit_cast(unsigned short, h);
}
__device__ __forceinline__ float h2f(unsigned short u) {
  return (float)__builtin_bit_cast(_Float16, u);
}
__device__ __forceinline__ f16x8 ld8(const unsigned short* p) {
  u32x4 v = *reinterpret_cast<const u32x4*>(p);
  return __builtin_bit_cast(f16x8, v);
}
__device__ __forceinline__ void gload_lds16(const unsigned short* g, unsigned short* l) {
  __builtin_amdgcn_global_load_lds(
      (const __attribute__((address_space(1))) unsigned int*)g,
      (__attribute__((address_space(3))) unsigned int*)l, 16, 0, 0);
}

// ---------------- fp32 -> fp16 convert ----------------
__global__ __launch_bounds__(256) void cvt_f32_f16(const float* __restrict__ in,
                                                   unsigned short* __restrict__ out, int n4) {
  int i = blockIdx.x * 256 + threadIdx.x;
  if (i >= n4) return;
  f32x4 v = *reinterpret_cast<const f32x4*>(in + (long)i * 4);
  u16x4 o;
  o.x = f2h_bits(v.x); o.y = f2h_bits(v.y); o.z = f2h_bits(v.z); o.w = f2h_bits(v.w);
  *reinterpret_cast<u16x4*>(out + (long)i * 4) = o;
}

// ---------------- RoPE tables (fp32) ----------------
__global__ __launch_bounds__(256) void rope_tables(float* __restrict__ c, float* __restrict__ s) {
  int idx = blockIdx.x * 256 + threadIdx.x;
  if (idx >= S_LEN * 16) return;
  int i = idx & 15, t = idx >> 4;
  // inv_freq = 10000^(-i/16) = 2^(-i * log2(10000)/16)
  float inv = exp2f(-(float)i * (13.287712379549449f / 16.0f));
  float f = (float)t * inv;
  c[idx] = cosf(f);
  s[idx] = sinf(f);
}

// ---------------- GEMM: C[m][n] = sum_k A[m][k]*B[n][k]  (both K-major, fp16) ----------------
template <typename OUT>
__global__ __launch_bounds__(256) void gemm_bt(const unsigned short* __restrict__ A,
                                               const unsigned short* __restrict__ B,
                                               OUT* __restrict__ C, int K, int ldc) {
  __shared__ unsigned short As[128 * 64];
  __shared__ unsigned short Bs[128 * 64];
  const int tid = threadIdx.x, wid = tid >> 6, lane = tid & 63;
  const int m0 = blockIdx.x * 128, n0 = blockIdx.y * 128;
  const int wr = (wid >> 1) * 64, wc = (wid & 1) * 64;
  const int rlo = lane & 15, rhi8 = (lane >> 4) * 8;
  const int srow = lane >> 3, scol = (lane & 7) * 8;
  f32x4 acc[4][4] = {};
  for (int k0 = 0; k0 < K; k0 += 64) {
#pragma unroll
    for (int i = 0; i < 4; ++i) {
      int chunk = wid * 4 + i;
      int row = chunk * 8 + srow;
      gload_lds16(A + (long)(m0 + row) * K + k0 + scol, &As[chunk * 512]);
      gload_lds16(B + (long)(n0 + row) * K + k0 + scol, &Bs[chunk * 512]);
    }
    __syncthreads();
#pragma unroll
    for (int kk = 0; kk < 64; kk += 32) {
      f16x8 af[4], bfr[4];
#pragma unroll
      for (int t = 0; t < 4; ++t) {
        af[t] = ld8(&As[(wr + t * 16 + rlo) * 64 + kk + rhi8]);
        bfr[t] = ld8(&Bs[(wc + t * 16 + rlo) * 64 + kk + rhi8]);
      }
#pragma unroll
      for (int mt = 0; mt < 4; ++mt)
#pragma unroll
        for (int nt = 0; nt < 4; ++nt)
          acc[mt][nt] = __builtin_amdgcn_mfma_f32_16x16x32_f16(af[mt], bfr[nt], acc[mt][nt], 0, 0, 0);
    }
    __syncthreads();
  }
#pragma unroll
  for (int mt = 0; mt < 4; ++mt)
#pragma unroll
    for (int nt = 0; nt < 4; ++nt) {
      int col = n0 + wc + nt * 16 + rlo;
#pragma unroll
      for (int r = 0; r < 4; ++r) {
        int row = m0 + wr + mt * 16 + (lane >> 4) * 4 + r;
        float v = acc[mt][nt][r];
        if constexpr (std::is_same<OUT, float>::value)
          C[(long)row * ldc + col] = v;
        else
          C[(long)row * ldc + col] = f2h_bits(v);
      }
    }
}

// ---------------- RMSNorm + RoPE + gain, scatter into Q/K layouts ----------------
// rows 0..B*S*NH-1: q rows (row = m*16 + h); rows after: k rows (row' = m*4 + kvh)
__global__ __launch_bounds__(256) void qknorm_rope(const unsigned short* __restrict__ qkv,
                                                   const float* __restrict__ ctab,
                                                   const float* __restrict__ stab,
                                                   const float* __restrict__ qgain,
                                                   unsigned short* __restrict__ Qb,
                                                   unsigned short* __restrict__ Kb) {
  const int lane = threadIdx.x & 63;
  const int row = blockIdx.x * 4 + (threadIdx.x >> 6);
  const int NQROWS = BATCH * S_LEN * NH;
  const unsigned short* src;
  unsigned short* dst;
  int m, hh;
  bool isQ;
  if (row < NQROWS) {
    m = row >> 4; hh = row & 15;
    src = qkv + (long)m * 3072 + hh * HD;
    int b = m >> 11, s = m & (S_LEN - 1);
    dst = Qb + (((long)(b * NH + hh)) * S_LEN + s) * HD;
    isQ = true;
  } else {
    int rk = row - NQROWS;
    m = rk >> 2; hh = rk & 3;
    src = qkv + (long)m * 3072 + 2048 + hh * HD;
    int b = m >> 11, s = m & (S_LEN - 1);
    dst = Kb + (((long)(b * NKV + hh)) * S_LEN + s) * HD;
    isQ = false;
  }
  const int s = m & (S_LEN - 1);
  float x0 = h2f(src[lane]);
  float x1 = h2f(src[lane + 64]);
  float ss = x0 * x0 + x1 * x1;
  ss += __shfl_xor(ss, 1); ss += __shfl_xor(ss, 2); ss += __shfl_xor(ss, 4);
  ss += __shfl_xor(ss, 8); ss += __shfl_xor(ss, 16); ss += __shfl_xor(ss, 32);
  float rn = rsqrtf(ss * (1.0f / 128.0f) + 1.1920929e-07f);
  float n0 = x0 * rn, n1 = x1 * rn;
  float partner = __shfl_xor(n0, 16);
  if (lane < 32) {
    int i = lane & 15;
    float c = ctab[s * 16 + i], sn = stab[s * 16 + i];
    n0 = (lane < 16) ? (n0 * c + partner * sn) : (n0 * c - partner * sn);
  }
  if (isQ) { float g = qgain[hh]; n0 *= g; n1 *= g; }
  dst[lane] = f2h_bits(n0);
  dst[lane + 64] = f2h_bits(n1);
}

// ---------------- V transpose: qkv v-block -> Vt[b][kvh][d][s] ----------------
__global__ __launch_bounds__(256) void vtrans(const unsigned short* __restrict__ qkv,
                                              unsigned short* __restrict__ Vt) {
  int idx = blockIdx.x * 256 + threadIdx.x;  // 2*4*128*256 = 262144
  int d = idx & 127;
  int sc = (idx >> 7) & 255;
  int kvh = (idx >> 15) & 3;
  int b = idx >> 17;
  u16x8 v;
#pragma unroll
  for (int j = 0; j < 8; ++j)
    v[j] = qkv[((long)(b * S_LEN + sc * 8 + j)) * 3072 + 2560 + kvh * HD + d];
  *reinterpret_cast<u16x8*>(Vt + (((long)(b * NKV + kvh)) * HD + d) * S_LEN + sc * 8) = v;
}

// ---------------- causal GQA attention with softcap ----------------
__global__ __launch_bounds__(256) void attn(const unsigned short* __restrict__ Qb,
                                            const unsigned short* __restrict__ Kb,
                                            const unsigned short* __restrict__ Vt,
                                            unsigned short* __restrict__ Yb) {
  __shared__ unsigned short Plds[4][16 * 48];
  const int tid = threadIdx.x, wid = tid >> 6, lane = tid & 63;
  const int qt = blockIdx.x, h = blockIdx.y, b = blockIdx.z;
  const int kvh = h >> 2;
  const int q0 = qt * 64 + wid * 16;
  const int rlo = lane & 15, rhi8 = (lane >> 4) * 8;
  const unsigned short* Qp = Qb + (((long)(b * NH + h)) * S_LEN + q0) * HD;
  const unsigned short* Kp = Kb + ((long)(b * NKV + kvh)) * S_LEN * HD;
  const unsigned short* Vp = Vt + ((long)(b * NKV + kvh)) * HD * S_LEN;
  f16x8 aq[4];
#pragma unroll
  for (int dk = 0; dk < 4; ++dk) aq[dk] = ld8(Qp + rlo * HD + dk * 32 + rhi8);
  f32x4 accO[8] = {};
  float m_run[4], l_run[4];
#pragma unroll
  for (int r = 0; r < 4; ++r) { m_run[r] = -1e30f; l_run[r] = 0.f; }
  const int qrow_base = q0 + (lane >> 4) * 4;
  const int ntile = (q0 + 16 + 31) >> 5;
  for (int t = 0; t < ntile; ++t) {
    const int k0 = t * 32;
    float sv[2][4];
#pragma unroll
    for (int half = 0; half < 2; ++half) {
      f32x4 sc = {0.f, 0.f, 0.f, 0.f};
      int kvcol = k0 + half * 16 + rlo;
      const unsigned short* kr = Kp + (long)kvcol * HD + rhi8;
#pragma unroll
      for (int dk = 0; dk < 4; ++dk)
        sc = __builtin_amdgcn_mfma_f32_16x16x32_f16(aq[dk], ld8(kr + dk * 32), sc, 0, 0, 0);
#pragma unroll
      for (int r = 0; r < 4; ++r) {
        float z = sc[r] * 0.08838834764831845f;      // *1/sqrt(128)
        float e = __expf(z * (2.0f / 30.0f));        // e^{2z/30}
        float s = 30.0f - 60.0f / (e + 1.0f);        // 30*tanh(z/30)
        sv[half][r] = (kvcol <= qrow_base + r) ? s : -1e30f;
      }
    }
#pragma unroll
    for (int r = 0; r < 4; ++r) {
      float mx = fmaxf(sv[0][r], sv[1][r]);
      mx = fmaxf(mx, __shfl_xor(mx, 1));
      mx = fmaxf(mx, __shfl_xor(mx, 2));
      mx = fmaxf(mx, __shfl_xor(mx, 4));
      mx = fmaxf(mx, __shfl_xor(mx, 8));
      float mnew = fmaxf(m_run[r], mx);
      float f = __expf(m_run[r] - mnew);
      m_run[r] = mnew;
      float p0 = __expf(sv[0][r] - mnew);
      float p1 = __expf(sv[1][r] - mnew);
      l_run[r] = l_run[r] * f + p0 + p1;
      int qloc = (lane >> 4) * 4 + r;
      Plds[wid][qloc * 48 + rlo] = f2h_bits(p0);
      Plds[wid][qloc * 48 + 16 + rlo] = f2h_bits(p1);
#pragma unroll
      for (int dt = 0; dt < 8; ++dt) accO[dt][r] *= f;
    }
    f16x8 ap = ld8(&Plds[wid][rlo * 48 + rhi8]);
#pragma unroll
    for (int dt = 0; dt < 8; ++dt) {
      f16x8 bv = ld8(Vp + (long)(dt * 16 + rlo) * S_LEN + k0 + rhi8);
      accO[dt] = __builtin_amdgcn_mfma_f32_16x16x32_f16(ap, bv, accO[dt], 0, 0, 0);
    }
  }
#pragma unroll
  for (int r = 0; r < 4; ++r) {
    float s = l_run[r];
    s += __shfl_xor(s, 1); s += __shfl_xor(s, 2); s += __shfl_xor(s, 4); s += __shfl_xor(s, 8);
    l_run[r] = 1.0f / s;
  }
#pragma unroll
  for (int dt = 0; dt < 8; ++dt)
#pragma unroll
    for (int r = 0; r < 4; ++r) {
      int qrow = qrow_base + r;
      Yb[((long)(b * S_LEN + qrow)) * DIM + h * HD + dt * 16 + rlo] =
          f2h_bits(accO[dt][r] * l_run[r]);
    }
}

extern "C" void kernel_launch(void* const* d_in, const int* in_sizes, int n_in,
                              void* d_out, int out_size, void* d_ws, size_t ws_size,
                              hipStream_t stream) {
  const float* x = (const float*)d_in[0];
  const float* Wq = (const float*)d_in[1];
  const float* Wk = (const float*)d_in[2];
  const float* Wv = (const float*)d_in[3];
  const float* Wp = (const float*)d_in[4];
  const float* qg = (const float*)d_in[5];
  float* out = (float*)d_out;

  char* ws = (char*)d_ws;
  size_t off = 0;
  auto alloc = [&](size_t bytes) {
    char* p = ws + off;
    off += (bytes + 255) & ~(size_t)255;
    return p;
  };
  unsigned short* xb   = (unsigned short*)alloc(8388608ull * 2);   // x fp16 [4096][2048]
  unsigned short* wqkv = (unsigned short*)alloc(6291456ull * 2);   // [3072][2048]
  unsigned short* wpj  = (unsigned short*)alloc(4194304ull * 2);   // [2048][2048]
  unsigned short* qkv  = (unsigned short*)alloc(4096ull * 3072 * 2);
  unsigned short* Qb   = (unsigned short*)alloc(8388608ull * 2);   // [B][16][S][128]
  unsigned short* Kb   = (unsigned short*)alloc(2097152ull * 2);   // [B][4][S][128]
  unsigned short* Vt   = (unsigned short*)alloc(2097152ull * 2);   // [B][4][128][S]
  unsigned short* Yb   = (unsigned short*)alloc(8388608ull * 2);   // [4096][2048]
  float* ctab = (float*)alloc(32768ull * 4);
  float* stab = (float*)alloc(32768ull * 4);

  auto cvt = [&](const float* src, unsigned short* dst, int n) {
    int n4 = n / 4;
    cvt_f32_f16<<<(n4 + 255) / 256, 256, 0, stream>>>(src, dst, n4);
  };
  cvt(x, xb, 8388608);
  cvt(Wq, wqkv, 4194304);
  cvt(Wk, wqkv + 4194304, 1048576);
  cvt(Wv, wqkv + 5242880, 1048576);
  cvt(Wp, wpj, 4194304);
  rope_tables<<<128, 256, 0, stream>>>(ctab, stab);

  // qkv = x @ [Wq;Wk;Wv]^T : M=4096 N=3072 K=2048
  gemm_bt<unsigned short><<<dim3(32, 24), 256, 0, stream>>>(xb, wqkv, qkv, 2048, 3072);

  qknorm_rope<<<(BATCH * S_LEN * (NH + NKV)) / 4, 256, 0, stream>>>(qkv, ctab, stab, qg, Qb, Kb);
  vtrans<<<(BATCH * NKV * HD * (S_LEN / 8)) / 256, 256, 0, stream>>>(qkv, Vt);

  attn<<<dim3(S_LEN / 64, NH, BATCH), 256, 0, stream>>>(Qb, Kb, Vt, Yb);

  // out = y @ Wproj^T : M=4096 N=2048 K=2048
  gemm_bt<float><<<dim3(32, 16), 256, 0, stream>>>(Yb, wpj, out, 2048, 2048);
}

// Round 2
// 416.324 us; speedup vs baseline: 1.5590x; 1.5590x over previous
//
#include <hip/hip_runtime.h>
#include <type_traits>

#define BATCH 2
#define S_LEN 2048
#define DIM 2048
#define NH 16
#define NKV 4
#define HD 128

typedef _Float16 f16x8 __attribute__((ext_vector_type(8)));
typedef _Float16 f16x2 __attribute__((ext_vector_type(2)));
typedef float f32x4 __attribute__((ext_vector_type(4)));
typedef unsigned int u32x4 __attribute__((ext_vector_type(4)));
typedef unsigned short u16x4 __attribute__((ext_vector_type(4)));
typedef unsigned short u16x8 __attribute__((ext_vector_type(8)));

__device__ __forceinline__ unsigned short f2h_bits(float f) {
  _Float16 h = (_Float16)f;
  return __builtin_bit_cast(unsigned short, h);
}
__device__ __forceinline__ float h2f(unsigned short u) {
  return (float)__builtin_bit_cast(_Float16, u);
}
__device__ __forceinline__ f16x8 ld8(const unsigned short* p) {
  u32x4 v = *reinterpret_cast<const u32x4*>(p);
  return __builtin_bit_cast(f16x8, v);
}
__device__ __forceinline__ void gload_lds16(const unsigned short* g, unsigned short* l) {
  __builtin_amdgcn_global_load_lds(
      (const __attribute__((address_space(1))) unsigned int*)g,
      (__attribute__((address_space(3))) unsigned int*)l, 16, 0, 0);
}

// ---------------- fp32 -> fp16 convert ----------------
__global__ __launch_bounds__(256) void cvt_f32_f16(const float* __restrict__ in,
                                                   unsigned short* __restrict__ out, int n4) {
  int i = blockIdx.x * 256 + threadIdx.x;
  if (i >= n4) return;
  f32x4 v = *reinterpret_cast<const f32x4*>(in + (long)i * 4);
  u16x4 o;
  o.x = f2h_bits(v.x); o.y = f2h_bits(v.y); o.z = f2h_bits(v.z); o.w = f2h_bits(v.w);
  *reinterpret_cast<u16x4*>(out + (long)i * 4) = o;
}

// ---------------- RoPE tables (fp32) ----------------
__global__ __launch_bounds__(256) void rope_tables(float* __restrict__ c, float* __restrict__ s) {
  int idx = blockIdx.x * 256 + threadIdx.x;
  if (idx >= S_LEN * 16) return;
  int i = idx & 15, t = idx >> 4;
  float inv = exp2f(-(float)i * (13.287712379549449f / 16.0f));
  float f = (float)t * inv;
  c[idx] = cosf(f);
  s[idx] = sinf(f);
}

// ---------------- GEMM: C[m][n] = sum_k A[m][k]*B[n][k]  (both K-major, fp16) ----------------
template <typename OUT>
__global__ __launch_bounds__(256) void gemm_bt(const unsigned short* __restrict__ A,
                                               const unsigned short* __restrict__ B,
                                               OUT* __restrict__ C, int K, int ldc) {
  __shared__ unsigned short As[128 * 64];
  __shared__ unsigned short Bs[128 * 64];
  const int tid = threadIdx.x, wid = tid >> 6, lane = tid & 63;
  const int m0 = blockIdx.x * 128, n0 = blockIdx.y * 128;
  const int wr = (wid >> 1) * 64, wc = (wid & 1) * 64;
  const int rlo = lane & 15, rhi8 = (lane >> 4) * 8;
  const int srow = lane >> 3, scol = (lane & 7) * 8;
  f32x4 acc[4][4] = {};
  for (int k0 = 0; k0 < K; k0 += 64) {
#pragma unroll
    for (int i = 0; i < 4; ++i) {
      int chunk = wid * 4 + i;
      int row = chunk * 8 + srow;
      gload_lds16(A + (long)(m0 + row) * K + k0 + scol, &As[chunk * 512]);
      gload_lds16(B + (long)(n0 + row) * K + k0 + scol, &Bs[chunk * 512]);
    }
    __syncthreads();
#pragma unroll
    for (int kk = 0; kk < 64; kk += 32) {
      f16x8 af[4], bfr[4];
#pragma unroll
      for (int t = 0; t < 4; ++t) {
        af[t] = ld8(&As[(wr + t * 16 + rlo) * 64 + kk + rhi8]);
        bfr[t] = ld8(&Bs[(wc + t * 16 + rlo) * 64 + kk + rhi8]);
      }
#pragma unroll
      for (int mt = 0; mt < 4; ++mt)
#pragma unroll
        for (int nt = 0; nt < 4; ++nt)
          acc[mt][nt] = __builtin_amdgcn_mfma_f32_16x16x32_f16(af[mt], bfr[nt], acc[mt][nt], 0, 0, 0);
    }
    __syncthreads();
  }
#pragma unroll
  for (int mt = 0; mt < 4; ++mt)
#pragma unroll
    for (int nt = 0; nt < 4; ++nt) {
      int col = n0 + wc + nt * 16 + rlo;
#pragma unroll
      for (int r = 0; r < 4; ++r) {
        int row = m0 + wr + mt * 16 + (lane >> 4) * 4 + r;
        float v = acc[mt][nt][r];
        if constexpr (std::is_same<OUT, float>::value)
          C[(long)row * ldc + col] = v;
        else
          C[(long)row * ldc + col] = f2h_bits(v);
      }
    }
}

// ---------------- RMSNorm + RoPE + gain, scatter into Q/K layouts ----------------
__global__ __launch_bounds__(256) void qknorm_rope(const unsigned short* __restrict__ qkv,
                                                   const float* __restrict__ ctab,
                                                   const float* __restrict__ stab,
                                                   const float* __restrict__ qgain,
                                                   unsigned short* __restrict__ Qb,
                                                   unsigned short* __restrict__ Kb) {
  const int lane = threadIdx.x & 63;
  const int row = blockIdx.x * 4 + (threadIdx.x >> 6);
  const int NQROWS = BATCH * S_LEN * NH;
  const unsigned short* src;
  unsigned short* dst;
  int m, hh;
  bool isQ;
  if (row < NQROWS) {
    m = row >> 4; hh = row & 15;
    src = qkv + (long)m * 3072 + hh * HD;
    int b = m >> 11, s = m & (S_LEN - 1);
    dst = Qb + (((long)(b * NH + hh)) * S_LEN + s) * HD;
    isQ = true;
  } else {
    int rk = row - NQROWS;
    m = rk >> 2; hh = rk & 3;
    src = qkv + (long)m * 3072 + 2048 + hh * HD;
    int b = m >> 11, s = m & (S_LEN - 1);
    dst = Kb + (((long)(b * NKV + hh)) * S_LEN + s) * HD;
    isQ = false;
  }
  const int s = m & (S_LEN - 1);
  float x0 = h2f(src[lane]);
  float x1 = h2f(src[lane + 64]);
  float ss = x0 * x0 + x1 * x1;
  ss += __shfl_xor(ss, 1); ss += __shfl_xor(ss, 2); ss += __shfl_xor(ss, 4);
  ss += __shfl_xor(ss, 8); ss += __shfl_xor(ss, 16); ss += __shfl_xor(ss, 32);
  float rn = rsqrtf(ss * (1.0f / 128.0f) + 1.1920929e-07f);
  float n0 = x0 * rn, n1 = x1 * rn;
  float partner = __shfl_xor(n0, 16);
  if (lane < 32) {
    int i = lane & 15;
    float c = ctab[s * 16 + i], sn = stab[s * 16 + i];
    n0 = (lane < 16) ? (n0 * c + partner * sn) : (n0 * c - partner * sn);
  }
  if (isQ) { float g = qgain[hh]; n0 *= g; n1 *= g; }
  dst[lane] = f2h_bits(n0);
  dst[lane + 64] = f2h_bits(n1);
}

// ---------------- V transpose: qkv v-block -> Vt[b][kvh][d][s] ----------------
__global__ __launch_bounds__(256) void vtrans(const unsigned short* __restrict__ qkv,
                                              unsigned short* __restrict__ Vt) {
  int idx = blockIdx.x * 256 + threadIdx.x;
  int d = idx & 127;
  int sc = (idx >> 7) & 255;
  int kvh = (idx >> 15) & 3;
  int b = idx >> 17;
  u16x8 v;
#pragma unroll
  for (int j = 0; j < 8; ++j)
    v[j] = qkv[((long)(b * S_LEN + sc * 8 + j)) * 3072 + 2560 + kvh * HD + d];
  *reinterpret_cast<u16x8*>(Vt + (((long)(b * NKV + kvh)) * HD + d) * S_LEN + sc * 8) = v;
}

// ---------------- causal GQA attention: swapped-operand, lane-local softmax ----------------
// Constants (log2 domain): C3 = scale*(2/30)*log2e ; earg = C4 - C5*rcp(u+1) - m2
#define ATT_C3 ((float)(0.08838834764831845 * (2.0 / 30.0) * 1.4426950408889634))
#define ATT_C4 ((float)(30.0 * 1.4426950408889634))
#define ATT_C5 ((float)(60.0 * 1.4426950408889634))
#define ATT_THR ((float)(8.0 * 1.4426950408889634))

__global__ __launch_bounds__(256, 4) void attn(const unsigned short* __restrict__ Qb,
                                               const unsigned short* __restrict__ Kb,
                                               const unsigned short* __restrict__ Vt,
                                               unsigned short* __restrict__ Yb) {
  const int tid = threadIdx.x, wid = tid >> 6, lane = tid & 63;
  const int pr = blockIdx.x, h = blockIdx.y, b = blockIdx.z;
  const int kvh = h >> 2;
  // balanced pairing: waves 0,1 -> tiles 2p,2p+1 ; waves 2,3 -> tiles 127-2p,126-2p
  const int jt = (wid < 2) ? (2 * pr + wid) : (127 - 2 * pr - (wid & 1));
  const int q0 = jt * 16;
  const int rlo = lane & 15, hi = lane >> 4;
  const unsigned short* Qp = Qb + (((long)(b * NH + h)) * S_LEN + q0) * HD;
  const unsigned short* Kp = Kb + ((long)(b * NKV + kvh)) * S_LEN * HD;
  const unsigned short* Vp = Vt + ((long)(b * NKV + kvh)) * HD * S_LEN;
  // Q as B-operand: B[k=hd][col=q] -> lane holds Q[q0+rlo][dk*32 + hi*8 + j]
  f16x8 bq[4];
#pragma unroll
  for (int dk = 0; dk < 4; ++dk) bq[dk] = ld8(Qp + rlo * HD + dk * 32 + hi * 8);
  // interleaved K-row assignment so P ends up kv-contiguous per lane:
  // half0 A-row rlo <- kv k0 + 8*(rlo>>2) + (rlo&3); half1 same +4
  const int krow = 8 * (rlo >> 2) + (rlo & 3);
  const int q_idx = q0 + rlo;
  f32x4 accO[8] = {};
  float m2c = ATT_C4 + 128.0f;  // = C4 - m2, with m2 initialized to -128 (log2 units)
  float l_run = 0.0f;
  const int nt = (q0 + 47) >> 5;
  for (int t = 0; t < nt; ++t) {
    const int k0 = t * 32;
    // --- QK^T (swapped): C[kv][q], lane -> q=rlo, kv = k0 + 8*hi + {0..3}(s0) {4..7}(s1)
    f32x4 s0 = {0.f, 0.f, 0.f, 0.f}, s1 = {0.f, 0.f, 0.f, 0.f};
    const unsigned short* kr = Kp + (long)(k0 + krow) * HD + hi * 8;
#pragma unroll
    for (int dk = 0; dk < 4; ++dk) {
      s0 = __builtin_amdgcn_mfma_f32_16x16x32_f16(ld8(kr + dk * 32), bq[dk], s0, 0, 0, 0);
      s1 = __builtin_amdgcn_mfma_f32_16x16x32_f16(ld8(kr + 4 * HD + dk * 32), bq[dk], s1, 0, 0, 0);
    }
    // V loads issued early (independent of softmax)
    f16x8 av[8];
#pragma unroll
    for (int dt = 0; dt < 8; ++dt) av[dt] = ld8(Vp + (long)(dt * 16 + rlo) * S_LEN + k0 + hi * 8);
    // --- softcap -> exponent arg in log2 domain (per-lane, q = rlo, kv = k0+8*hi+j)
    float ea[8];
#pragma unroll
    for (int j = 0; j < 8; ++j) {
      float sc = (j < 4) ? s0[j] : s1[j - 4];
      float u = __builtin_amdgcn_exp2f(sc * ATT_C3);
      float rr = __builtin_amdgcn_rcpf(u + 1.0f);
      ea[j] = fmaf(-ATT_C5, rr, m2c);
    }
    if (t == nt - 1) {
#pragma unroll
      for (int j = 0; j < 8; ++j)
        ea[j] = (k0 + 8 * hi + j > q_idx) ? -1e30f : ea[j];
    }
    // --- T13 defer-max: common path has no reduce, no rescale
    float pm = ea[0];
#pragma unroll
    for (int j = 1; j < 8; ++j) pm = fmaxf(pm, ea[j]);
    if (!__all(pm <= ATT_THR)) {  // wave-uniform rare path
      float red = fmaxf(pm, __shfl_xor(pm, 16));
      red = fmaxf(red, __shfl_xor(red, 32));
      red = fmaxf(red, 0.0f);
      m2c -= red;
      float f = __builtin_amdgcn_exp2f(-red);
      l_run *= f;
#pragma unroll
      for (int dt = 0; dt < 8; ++dt) accO[dt] *= f;
#pragma unroll
      for (int j = 0; j < 8; ++j) ea[j] -= red;
    }
    float p[8];
#pragma unroll
    for (int j = 0; j < 8; ++j) p[j] = __builtin_amdgcn_exp2f(ea[j]);
    l_run += ((p[0] + p[1]) + (p[2] + p[3])) + ((p[4] + p[5]) + (p[6] + p[7]));
    // --- pack P (lane already holds kv k0+8*hi+0..7 for its q): 4 cvt_pkrtz, no shuffles
    u32x4 pk;
    pk.x = __builtin_bit_cast(unsigned int, __builtin_amdgcn_cvt_pkrtz(p[0], p[1]));
    pk.y = __builtin_bit_cast(unsigned int, __builtin_amdgcn_cvt_pkrtz(p[2], p[3]));
    pk.z = __builtin_bit_cast(unsigned int, __builtin_amdgcn_cvt_pkrtz(p[4], p[5]));
    pk.w = __builtin_bit_cast(unsigned int, __builtin_amdgcn_cvt_pkrtz(p[6], p[7]));
    f16x8 bp = __builtin_bit_cast(f16x8, pk);
    // --- PV (swapped): C'[d][q] = Vt·P^T ; lane -> q=rlo, d rows 4*hi+r per dt block
#pragma unroll
    for (int dt = 0; dt < 8; ++dt)
      accO[dt] = __builtin_amdgcn_mfma_f32_16x16x32_f16(av[dt], bp, accO[dt], 0, 0, 0);
  }
  // finalize: combine l across the 4 lanes sharing this q (disjoint kv subsets)
  float l = l_run + __shfl_xor(l_run, 16);
  l += __shfl_xor(l, 32);
  float inv = 1.0f / l;
  unsigned short* yp = Yb + ((long)(b * S_LEN + q_idx)) * DIM + h * HD + 4 * hi;
#pragma unroll
  for (int dt = 0; dt < 8; ++dt) {
    u16x4 o;
#pragma unroll
    for (int r = 0; r < 4; ++r) o[r] = f2h_bits(accO[dt][r] * inv);
    *reinterpret_cast<u16x4*>(yp + dt * 16) = o;
  }
}

extern "C" void kernel_launch(void* const* d_in, const int* in_sizes, int n_in,
                              void* d_out, int out_size, void* d_ws, size_t ws_size,
                              hipStream_t stream) {
  const float* x = (const float*)d_in[0];
  const float* Wq = (const float*)d_in[1];
  const float* Wk = (const float*)d_in[2];
  const float* Wv = (const float*)d_in[3];
  const float* Wp = (const float*)d_in[4];
  const float* qg = (const float*)d_in[5];
  float* out = (float*)d_out;

  char* ws = (char*)d_ws;
  size_t off = 0;
  auto alloc = [&](size_t bytes) {
    char* p = ws + off;
    off += (bytes + 255) & ~(size_t)255;
    return p;
  };
  unsigned short* xb   = (unsigned short*)alloc(8388608ull * 2);
  unsigned short* wqkv = (unsigned short*)alloc(6291456ull * 2);
  unsigned short* wpj  = (unsigned short*)alloc(4194304ull * 2);
  unsigned short* qkv  = (unsigned short*)alloc(4096ull * 3072 * 2);
  unsigned short* Qb   = (unsigned short*)alloc(8388608ull * 2);
  unsigned short* Kb   = (unsigned short*)alloc(2097152ull * 2);
  unsigned short* Vt   = (unsigned short*)alloc(2097152ull * 2);
  unsigned short* Yb   = (unsigned short*)alloc(8388608ull * 2);
  float* ctab = (float*)alloc(32768ull * 4);
  float* stab = (float*)alloc(32768ull * 4);

  auto cvt = [&](const float* src, unsigned short* dst, int n) {
    int n4 = n / 4;
    cvt_f32_f16<<<(n4 + 255) / 256, 256, 0, stream>>>(src, dst, n4);
  };
  cvt(x, xb, 8388608);
  cvt(Wq, wqkv, 4194304);
  cvt(Wk, wqkv + 4194304, 1048576);
  cvt(Wv, wqkv + 5242880, 1048576);
  cvt(Wp, wpj, 4194304);
  rope_tables<<<128, 256, 0, stream>>>(ctab, stab);

  gemm_bt<unsigned short><<<dim3(32, 24), 256, 0, stream>>>(xb, wqkv, qkv, 2048, 3072);

  qknorm_rope<<<(BATCH * S_LEN * (NH + NKV)) / 4, 256, 0, stream>>>(qkv, ctab, stab, qg, Qb, Kb);
  vtrans<<<(BATCH * NKV * HD * (S_LEN / 8)) / 256, 256, 0, stream>>>(qkv, Vt);

  attn<<<dim3(32, NH, BATCH), 256, 0, stream>>>(Qb, Kb, Vt, Yb);

  gemm_bt<float><<<dim3(32, 16), 256, 0, stream>>>(Yb, wpj, out, 2048, 2048);
}

// Round 3
// 295.377 us; speedup vs baseline: 2.1974x; 1.4095x over previous
//
#include <hip/hip_runtime.h>
#include <type_traits>

#define BATCH 2
#define S_LEN 2048
#define DIM 2048
#define NH 16
#define NKV 4
#define HD 128

typedef _Float16 f16x8 __attribute__((ext_vector_type(8)));
typedef float f32x4 __attribute__((ext_vector_type(4)));
typedef unsigned int u32x4 __attribute__((ext_vector_type(4)));
typedef unsigned short u16x4 __attribute__((ext_vector_type(4)));
typedef unsigned short u16x8 __attribute__((ext_vector_type(8)));

__device__ __forceinline__ unsigned short f2h_bits(float f) {
  _Float16 h = (_Float16)f;
  return __builtin_bit_cast(unsigned short, h);
}
__device__ __forceinline__ float h2f(unsigned short u) {
  return (float)__builtin_bit_cast(_Float16, u);
}
__device__ __forceinline__ f16x8 ld8(const unsigned short* p) {
  u32x4 v = *reinterpret_cast<const u32x4*>(p);
  return __builtin_bit_cast(f16x8, v);
}
__device__ __forceinline__ void gload_lds16(const unsigned short* g, unsigned short* l) {
  __builtin_amdgcn_global_load_lds(
      (const __attribute__((address_space(1))) unsigned int*)g,
      (__attribute__((address_space(3))) unsigned int*)l, 16, 0, 0);
}

// ---------------- fp32 -> fp16 convert ----------------
__global__ __launch_bounds__(256) void cvt_f32_f16(const float* __restrict__ in,
                                                   unsigned short* __restrict__ out, int n4) {
  int i = blockIdx.x * 256 + threadIdx.x;
  if (i >= n4) return;
  f32x4 v = *reinterpret_cast<const f32x4*>(in + (long)i * 4);
  u16x4 o;
  o.x = f2h_bits(v.x); o.y = f2h_bits(v.y); o.z = f2h_bits(v.z); o.w = f2h_bits(v.w);
  *reinterpret_cast<u16x4*>(out + (long)i * 4) = o;
}

// ---------------- RoPE tables (fp32) ----------------
__global__ __launch_bounds__(256) void rope_tables(float* __restrict__ c, float* __restrict__ s) {
  int idx = blockIdx.x * 256 + threadIdx.x;
  if (idx >= S_LEN * 16) return;
  int i = idx & 15, t = idx >> 4;
  float inv = exp2f(-(float)i * (13.287712379549449f / 16.0f));
  float f = (float)t * inv;
  c[idx] = cosf(f);
  s[idx] = sinf(f);
}

// ---------------- GEMM: C[m][n] = sum_k A[m][k]*B[n][k]  (both K-major, fp16) ----------------
template <typename OUT>
__global__ __launch_bounds__(256) void gemm_bt(const unsigned short* __restrict__ A,
                                               const unsigned short* __restrict__ B,
                                               OUT* __restrict__ C, int K, int ldc) {
  __shared__ unsigned short As[128 * 64];
  __shared__ unsigned short Bs[128 * 64];
  const int tid = threadIdx.x, wid = tid >> 6, lane = tid & 63;
  const int m0 = blockIdx.x * 128, n0 = blockIdx.y * 128;
  const int wr = (wid >> 1) * 64, wc = (wid & 1) * 64;
  const int rlo = lane & 15, rhi8 = (lane >> 4) * 8;
  const int srow = lane >> 3, scol = (lane & 7) * 8;
  f32x4 acc[4][4] = {};
  for (int k0 = 0; k0 < K; k0 += 64) {
#pragma unroll
    for (int i = 0; i < 4; ++i) {
      int chunk = wid * 4 + i;
      int row = chunk * 8 + srow;
      gload_lds16(A + (long)(m0 + row) * K + k0 + scol, &As[chunk * 512]);
      gload_lds16(B + (long)(n0 + row) * K + k0 + scol, &Bs[chunk * 512]);
    }
    __syncthreads();
#pragma unroll
    for (int kk = 0; kk < 64; kk += 32) {
      f16x8 af[4], bfr[4];
#pragma unroll
      for (int t = 0; t < 4; ++t) {
        af[t] = ld8(&As[(wr + t * 16 + rlo) * 64 + kk + rhi8]);
        bfr[t] = ld8(&Bs[(wc + t * 16 + rlo) * 64 + kk + rhi8]);
      }
#pragma unroll
      for (int mt = 0; mt < 4; ++mt)
#pragma unroll
        for (int nt = 0; nt < 4; ++nt)
          acc[mt][nt] = __builtin_amdgcn_mfma_f32_16x16x32_f16(af[mt], bfr[nt], acc[mt][nt], 0, 0, 0);
    }
    __syncthreads();
  }
#pragma unroll
  for (int mt = 0; mt < 4; ++mt)
#pragma unroll
    for (int nt = 0; nt < 4; ++nt) {
      int col = n0 + wc + nt * 16 + rlo;
#pragma unroll
      for (int r = 0; r < 4; ++r) {
        int row = m0 + wr + mt * 16 + (lane >> 4) * 4 + r;
        float v = acc[mt][nt][r];
        if constexpr (std::is_same<OUT, float>::value)
          C[(long)row * ldc + col] = v;
        else
          C[(long)row * ldc + col] = f2h_bits(v);
      }
    }
}

// ---------------- RMSNorm + RoPE + gain, scatter into Q/K layouts ----------------
__global__ __launch_bounds__(256) void qknorm_rope(const unsigned short* __restrict__ qkv,
                                                   const float* __restrict__ ctab,
                                                   const float* __restrict__ stab,
                                                   const float* __restrict__ qgain,
                                                   unsigned short* __restrict__ Qb,
                                                   unsigned short* __restrict__ Kb) {
  const int lane = threadIdx.x & 63;
  const int row = blockIdx.x * 4 + (threadIdx.x >> 6);
  const int NQROWS = BATCH * S_LEN * NH;
  const unsigned short* src;
  unsigned short* dst;
  int m, hh;
  bool isQ;
  if (row < NQROWS) {
    m = row >> 4; hh = row & 15;
    src = qkv + (long)m * 3072 + hh * HD;
    int b = m >> 11, s = m & (S_LEN - 1);
    dst = Qb + (((long)(b * NH + hh)) * S_LEN + s) * HD;
    isQ = true;
  } else {
    int rk = row - NQROWS;
    m = rk >> 2; hh = rk & 3;
    src = qkv + (long)m * 3072 + 2048 + hh * HD;
    int b = m >> 11, s = m & (S_LEN - 1);
    dst = Kb + (((long)(b * NKV + hh)) * S_LEN + s) * HD;
    isQ = false;
  }
  const int s = m & (S_LEN - 1);
  float x0 = h2f(src[lane]);
  float x1 = h2f(src[lane + 64]);
  float ss = x0 * x0 + x1 * x1;
  ss += __shfl_xor(ss, 1); ss += __shfl_xor(ss, 2); ss += __shfl_xor(ss, 4);
  ss += __shfl_xor(ss, 8); ss += __shfl_xor(ss, 16); ss += __shfl_xor(ss, 32);
  float rn = rsqrtf(ss * (1.0f / 128.0f) + 1.1920929e-07f);
  float n0 = x0 * rn, n1 = x1 * rn;
  float partner = __shfl_xor(n0, 16);
  if (lane < 32) {
    int i = lane & 15;
    float c = ctab[s * 16 + i], sn = stab[s * 16 + i];
    n0 = (lane < 16) ? (n0 * c + partner * sn) : (n0 * c - partner * sn);
  }
  if (isQ) { float g = qgain[hh]; n0 *= g; n1 *= g; }
  dst[lane] = f2h_bits(n0);
  dst[lane + 64] = f2h_bits(n1);
}

// ---------------- V transpose: qkv v-block -> Vt[b][kvh][d][s] ----------------
__global__ __launch_bounds__(256) void vtrans(const unsigned short* __restrict__ qkv,
                                              unsigned short* __restrict__ Vt) {
  int idx = blockIdx.x * 256 + threadIdx.x;
  int d = idx & 127;
  int sc = (idx >> 7) & 255;
  int kvh = (idx >> 15) & 3;
  int b = idx >> 17;
  u16x8 v;
#pragma unroll
  for (int j = 0; j < 8; ++j)
    v[j] = qkv[((long)(b * S_LEN + sc * 8 + j)) * 3072 + 2560 + kvh * HD + d];
  *reinterpret_cast<u16x8*>(Vt + (((long)(b * NKV + kvh)) * HD + d) * S_LEN + sc * 8) = v;
}

// ---------------- causal GQA attention: shared-KV LDS flash structure ----------------
#define ATT_C3 ((float)(0.08838834764831845 * (2.0 / 30.0) * 1.4426950408889634))
#define ATT_C4 ((float)(30.0 * 1.4426950408889634))
#define ATT_C5 ((float)(60.0 * 1.4426950408889634))
#define ATT_THR ((float)(8.0 * 1.4426950408889634))

__global__ __launch_bounds__(256, 4) void attn(const unsigned short* __restrict__ Qb,
                                               const unsigned short* __restrict__ Kb,
                                               const unsigned short* __restrict__ Vt,
                                               unsigned short* __restrict__ Yb) {
  // K tile [32 kv][128 hd], V tile [128 d][32 kv]; both double-buffered, XOR-swizzled
  __shared__ unsigned short Klds[2][32 * 128];
  __shared__ unsigned short Vlds[2][128 * 32];
  const int tid = threadIdx.x, wid = tid >> 6, lane = tid & 63;
  const int qb = 31 - blockIdx.x;  // biggest blocks dispatched first
  const int h = blockIdx.y, b = blockIdx.z;
  const int kvh = h >> 2;
  const int q0w = qb * 64 + wid * 16;
  const int rlo = lane & 15, hi = lane >> 4;
  const unsigned short* Qp = Qb + (((long)(b * NH + h)) * S_LEN + q0w) * HD;
  const unsigned short* Kp = Kb + ((long)(b * NKV + kvh)) * S_LEN * HD;
  const unsigned short* Vp = Vt + ((long)(b * NKV + kvh)) * HD * S_LEN;
  // Q as B-operand fragments (held in regs for the whole kernel)
  f16x8 bq[4];
#pragma unroll
  for (int dk = 0; dk < 4; ++dk) bq[dk] = ld8(Qp + rlo * HD + dk * 32 + hi * 8);
  // staging lane constants (LDS dest linear; inverse swizzle on global src — rule #21)
  const int kR0 = wid * 4 + (lane >> 4);                    // +16 for round 1
  const int kCh = (lane & 15) ^ ((kR0 & 8) >> 1);           // K swizzle: chunk ^ ((row&8)>>1)
  const int vD0 = wid * 16 + (lane >> 2);                   // +64 for round 1
  const int vCh = (lane & 3) ^ (vD0 & 3);                   // V swizzle: chunk ^ (d&3)
  const int krow = 8 * (rlo >> 2) + (rlo & 3);              // interleaved kv-row map (half0)
  const int q_idx = q0w + rlo;
  f32x4 accO[8] = {};
  float m2c = ATT_C4 + 128.0f;
  float l_run = 0.0f;
  const int nt = 2 * qb + 2;

  auto stage = [&](int buf, int k0) {
    gload_lds16(Kp + (long)(k0 + kR0) * HD + kCh * 8, &Klds[buf][(wid * 4) * 128]);
    gload_lds16(Kp + (long)(k0 + kR0 + 16) * HD + kCh * 8, &Klds[buf][(16 + wid * 4) * 128]);
    gload_lds16(Vp + (long)vD0 * S_LEN + k0 + vCh * 8, &Vlds[buf][(wid * 16) * 32]);
    gload_lds16(Vp + (long)(vD0 + 64) * S_LEN + k0 + vCh * 8, &Vlds[buf][(64 + wid * 16) * 32]);
  };

  stage(0, 0);
  __syncthreads();
  int buf = 0;
  for (int t = 0; t < nt; ++t) {
    const int k0 = t * 32;
    if (t + 1 < nt) stage(buf ^ 1, (t + 1) * 32);
    if (k0 <= q0w + 15) {  // wave-uniform: this wave still has unmasked kv here
      // --- QK^T from swizzled K_lds
      f32x4 s0 = {0.f, 0.f, 0.f, 0.f}, s1 = {0.f, 0.f, 0.f, 0.f};
      const int r1 = krow + 4;
      __builtin_amdgcn_s_setprio(1);
#pragma unroll
      for (int dk = 0; dk < 4; ++dk) {
        f16x8 a0 = ld8(&Klds[buf][krow * 128 + (((dk * 4 + hi) ^ ((krow & 8) >> 1)) * 8)]);
        f16x8 a1 = ld8(&Klds[buf][r1 * 128 + (((dk * 4 + hi) ^ ((r1 & 8) >> 1)) * 8)]);
        s0 = __builtin_amdgcn_mfma_f32_16x16x32_f16(a0, bq[dk], s0, 0, 0, 0);
        s1 = __builtin_amdgcn_mfma_f32_16x16x32_f16(a1, bq[dk], s1, 0, 0, 0);
      }
      __builtin_amdgcn_s_setprio(0);
      // --- softcap -> log2-domain exponent args (lane-local, q = rlo, kv = k0+8*hi+j)
      float ea[8];
#pragma unroll
      for (int j = 0; j < 8; ++j) {
        float sc = (j < 4) ? s0[j] : s1[j - 4];
        float u = __builtin_amdgcn_exp2f(sc * ATT_C3);
        float rr = __builtin_amdgcn_rcpf(u + 1.0f);
        ea[j] = fmaf(-ATT_C5, rr, m2c);
      }
      if (k0 + 31 > q0w) {  // only boundary tiles need masking
#pragma unroll
        for (int j = 0; j < 8; ++j)
          ea[j] = (k0 + 8 * hi + j > q_idx) ? -1e30f : ea[j];
      }
      // --- T13 defer-max
      float pm = ea[0];
#pragma unroll
      for (int j = 1; j < 8; ++j) pm = fmaxf(pm, ea[j]);
      if (!__all(pm <= ATT_THR)) {
        float red = fmaxf(pm, __shfl_xor(pm, 16));
        red = fmaxf(red, __shfl_xor(red, 32));
        red = fmaxf(red, 0.0f);
        m2c -= red;
        float f = __builtin_amdgcn_exp2f(-red);
        l_run *= f;
#pragma unroll
        for (int dt = 0; dt < 8; ++dt) accO[dt] *= f;
#pragma unroll
        for (int j = 0; j < 8; ++j) ea[j] -= red;
      }
      float p[8];
#pragma unroll
      for (int j = 0; j < 8; ++j) p[j] = __builtin_amdgcn_exp2f(ea[j]);
      l_run += ((p[0] + p[1]) + (p[2] + p[3])) + ((p[4] + p[5]) + (p[6] + p[7]));
      u32x4 pk;
      pk.x = __builtin_bit_cast(unsigned int, __builtin_amdgcn_cvt_pkrtz(p[0], p[1]));
      pk.y = __builtin_bit_cast(unsigned int, __builtin_amdgcn_cvt_pkrtz(p[2], p[3]));
      pk.z = __builtin_bit_cast(unsigned int, __builtin_amdgcn_cvt_pkrtz(p[4], p[5]));
      pk.w = __builtin_bit_cast(unsigned int, __builtin_amdgcn_cvt_pkrtz(p[6], p[7]));
      f16x8 bp = __builtin_bit_cast(f16x8, pk);
      // --- PV from swizzled V_lds (two halves of 4 to bound VGPR)
      __builtin_amdgcn_s_setprio(1);
#pragma unroll
      for (int g = 0; g < 2; ++g) {
        f16x8 av[4];
#pragma unroll
        for (int i = 0; i < 4; ++i) {
          int d = (g * 4 + i) * 16 + rlo;
          av[i] = ld8(&Vlds[buf][d * 32 + ((hi ^ (d & 3)) * 8)]);
        }
#pragma unroll
        for (int i = 0; i < 4; ++i)
          accO[g * 4 + i] = __builtin_amdgcn_mfma_f32_16x16x32_f16(av[i], bp, accO[g * 4 + i], 0, 0, 0);
      }
      __builtin_amdgcn_s_setprio(0);
    }
    __syncthreads();  // drains vmcnt (stage done) + all waves done reading buf
    buf ^= 1;
  }
  // finalize: combine l across the 4 hi-lanes sharing this q
  float l = l_run + __shfl_xor(l_run, 16);
  l += __shfl_xor(l, 32);
  float inv = 1.0f / l;
  unsigned short* yp = Yb + ((long)(b * S_LEN + q_idx)) * DIM + h * HD + 4 * hi;
#pragma unroll
  for (int dt = 0; dt < 8; ++dt) {
    u16x4 o;
#pragma unroll
    for (int r = 0; r < 4; ++r) o[r] = f2h_bits(accO[dt][r] * inv);
    *reinterpret_cast<u16x4*>(yp + dt * 16) = o;
  }
}

extern "C" void kernel_launch(void* const* d_in, const int* in_sizes, int n_in,
                              void* d_out, int out_size, void* d_ws, size_t ws_size,
                              hipStream_t stream) {
  const float* x = (const float*)d_in[0];
  const float* Wq = (const float*)d_in[1];
  const float* Wk = (const float*)d_in[2];
  const float* Wv = (const float*)d_in[3];
  const float* Wp = (const float*)d_in[4];
  const float* qg = (const float*)d_in[5];
  float* out = (float*)d_out;

  char* ws = (char*)d_ws;
  size_t off = 0;
  auto alloc = [&](size_t bytes) {
    char* p = ws + off;
    off += (bytes + 255) & ~(size_t)255;
    return p;
  };
  unsigned short* xb   = (unsigned short*)alloc(8388608ull * 2);
  unsigned short* wqkv = (unsigned short*)alloc(6291456ull * 2);
  unsigned short* wpj  = (unsigned short*)alloc(4194304ull * 2);
  unsigned short* qkv  = (unsigned short*)alloc(4096ull * 3072 * 2);
  unsigned short* Qb   = (unsigned short*)alloc(8388608ull * 2);
  unsigned short* Kb   = (unsigned short*)alloc(2097152ull * 2);
  unsigned short* Vt   = (unsigned short*)alloc(2097152ull * 2);
  unsigned short* Yb   = (unsigned short*)alloc(8388608ull * 2);
  float* ctab = (float*)alloc(32768ull * 4);
  float* stab = (float*)alloc(32768ull * 4);

  auto cvt = [&](const float* src, unsigned short* dst, int n) {
    int n4 = n / 4;
    cvt_f32_f16<<<(n4 + 255) / 256, 256, 0, stream>>>(src, dst, n4);
  };
  cvt(x, xb, 8388608);
  cvt(Wq, wqkv, 4194304);
  cvt(Wk, wqkv + 4194304, 1048576);
  cvt(Wv, wqkv + 5242880, 1048576);
  cvt(Wp, wpj, 4194304);
  rope_tables<<<128, 256, 0, stream>>>(ctab, stab);

  gemm_bt<unsigned short><<<dim3(32, 24), 256, 0, stream>>>(xb, wqkv, qkv, 2048, 3072);

  qknorm_rope<<<(BATCH * S_LEN * (NH + NKV)) / 4, 256, 0, stream>>>(qkv, ctab, stab, qg, Qb, Kb);
  vtrans<<<(BATCH * NKV * HD * (S_LEN / 8)) / 256, 256, 0, stream>>>(qkv, Vt);

  attn<<<dim3(32, NH, BATCH), 256, 0, stream>>>(Qb, Kb, Vt, Yb);

  gemm_bt<float><<<dim3(32, 16), 256, 0, stream>>>(Yb, wpj, out, 2048, 2048);
}

// Round 4
// 269.996 us; speedup vs baseline: 2.4040x; 1.0940x over previous
//
#include <hip/hip_runtime.h>
#include <type_traits>

#define BATCH 2
#define S_LEN 2048
#define DIM 2048
#define NH 16
#define NKV 4
#define HD 128

typedef _Float16 f16x8 __attribute__((ext_vector_type(8)));
typedef float f32x4 __attribute__((ext_vector_type(4)));
typedef unsigned int u32x4 __attribute__((ext_vector_type(4)));
typedef unsigned short u16x4 __attribute__((ext_vector_type(4)));
typedef unsigned short u16x8 __attribute__((ext_vector_type(8)));

__device__ __forceinline__ unsigned short f2h_bits(float f) {
  _Float16 h = (_Float16)f;
  return __builtin_bit_cast(unsigned short, h);
}
__device__ __forceinline__ float h2f(unsigned short u) {
  return (float)__builtin_bit_cast(_Float16, u);
}
__device__ __forceinline__ f16x8 ld8(const unsigned short* p) {
  u32x4 v = *reinterpret_cast<const u32x4*>(p);
  return __builtin_bit_cast(f16x8, v);
}
__device__ __forceinline__ void gload_lds16(const unsigned short* g, unsigned short* l) {
  __builtin_amdgcn_global_load_lds(
      (const __attribute__((address_space(1))) unsigned int*)g,
      (__attribute__((address_space(3))) unsigned int*)l, 16, 0, 0);
}

// ---------------- fp32 -> fp16 convert ----------------
__global__ __launch_bounds__(256) void cvt_f32_f16(const float* __restrict__ in,
                                                   unsigned short* __restrict__ out, int n4) {
  int i = blockIdx.x * 256 + threadIdx.x;
  if (i >= n4) return;
  f32x4 v = *reinterpret_cast<const f32x4*>(in + (long)i * 4);
  u16x4 o;
  o.x = f2h_bits(v.x); o.y = f2h_bits(v.y); o.z = f2h_bits(v.z); o.w = f2h_bits(v.w);
  *reinterpret_cast<u16x4*>(out + (long)i * 4) = o;
}

// ---------------- RoPE tables (fp32) ----------------
__global__ __launch_bounds__(256) void rope_tables(float* __restrict__ c, float* __restrict__ s) {
  int idx = blockIdx.x * 256 + threadIdx.x;
  if (idx >= S_LEN * 16) return;
  int i = idx & 15, t = idx >> 4;
  float inv = exp2f(-(float)i * (13.287712379549449f / 16.0f));
  float f = (float)t * inv;
  c[idx] = cosf(f);
  s[idx] = sinf(f);
}

// ---------------- GEMM: C[m][n] = sum_k A[m][k]*B[n][k]  (both K-major, fp16) ----------------
template <typename OUT>
__global__ __launch_bounds__(256) void gemm_bt(const unsigned short* __restrict__ A,
                                               const unsigned short* __restrict__ B,
                                               OUT* __restrict__ C, int K, int ldc) {
  __shared__ unsigned short As[128 * 64];
  __shared__ unsigned short Bs[128 * 64];
  const int tid = threadIdx.x, wid = tid >> 6, lane = tid & 63;
  const int m0 = blockIdx.x * 128, n0 = blockIdx.y * 128;
  const int wr = (wid >> 1) * 64, wc = (wid & 1) * 64;
  const int rlo = lane & 15, rhi8 = (lane >> 4) * 8;
  const int srow = lane >> 3, scol = (lane & 7) * 8;
  f32x4 acc[4][4] = {};
  for (int k0 = 0; k0 < K; k0 += 64) {
#pragma unroll
    for (int i = 0; i < 4; ++i) {
      int chunk = wid * 4 + i;
      int row = chunk * 8 + srow;
      gload_lds16(A + (long)(m0 + row) * K + k0 + scol, &As[chunk * 512]);
      gload_lds16(B + (long)(n0 + row) * K + k0 + scol, &Bs[chunk * 512]);
    }
    __syncthreads();
#pragma unroll
    for (int kk = 0; kk < 64; kk += 32) {
      f16x8 af[4], bfr[4];
#pragma unroll
      for (int t = 0; t < 4; ++t) {
        af[t] = ld8(&As[(wr + t * 16 + rlo) * 64 + kk + rhi8]);
        bfr[t] = ld8(&Bs[(wc + t * 16 + rlo) * 64 + kk + rhi8]);
      }
#pragma unroll
      for (int mt = 0; mt < 4; ++mt)
#pragma unroll
        for (int nt = 0; nt < 4; ++nt)
          acc[mt][nt] = __builtin_amdgcn_mfma_f32_16x16x32_f16(af[mt], bfr[nt], acc[mt][nt], 0, 0, 0);
    }
    __syncthreads();
  }
#pragma unroll
  for (int mt = 0; mt < 4; ++mt)
#pragma unroll
    for (int nt = 0; nt < 4; ++nt) {
      int col = n0 + wc + nt * 16 + rlo;
#pragma unroll
      for (int r = 0; r < 4; ++r) {
        int row = m0 + wr + mt * 16 + (lane >> 4) * 4 + r;
        float v = acc[mt][nt][r];
        if constexpr (std::is_same<OUT, float>::value)
          C[(long)row * ldc + col] = v;
        else
          C[(long)row * ldc + col] = f2h_bits(v);
      }
    }
}

// ---------------- RMSNorm + RoPE + gain, scatter into Q/K layouts ----------------
__global__ __launch_bounds__(256) void qknorm_rope(const unsigned short* __restrict__ qkv,
                                                   const float* __restrict__ ctab,
                                                   const float* __restrict__ stab,
                                                   const float* __restrict__ qgain,
                                                   unsigned short* __restrict__ Qb,
                                                   unsigned short* __restrict__ Kb) {
  const int lane = threadIdx.x & 63;
  const int row = blockIdx.x * 4 + (threadIdx.x >> 6);
  const int NQROWS = BATCH * S_LEN * NH;
  const unsigned short* src;
  unsigned short* dst;
  int m, hh;
  bool isQ;
  if (row < NQROWS) {
    m = row >> 4; hh = row & 15;
    src = qkv + (long)m * 3072 + hh * HD;
    int b = m >> 11, s = m & (S_LEN - 1);
    dst = Qb + (((long)(b * NH + hh)) * S_LEN + s) * HD;
    isQ = true;
  } else {
    int rk = row - NQROWS;
    m = rk >> 2; hh = rk & 3;
    src = qkv + (long)m * 3072 + 2048 + hh * HD;
    int b = m >> 11, s = m & (S_LEN - 1);
    dst = Kb + (((long)(b * NKV + hh)) * S_LEN + s) * HD;
    isQ = false;
  }
  const int s = m & (S_LEN - 1);
  float x0 = h2f(src[lane]);
  float x1 = h2f(src[lane + 64]);
  float ss = x0 * x0 + x1 * x1;
  ss += __shfl_xor(ss, 1); ss += __shfl_xor(ss, 2); ss += __shfl_xor(ss, 4);
  ss += __shfl_xor(ss, 8); ss += __shfl_xor(ss, 16); ss += __shfl_xor(ss, 32);
  float rn = rsqrtf(ss * (1.0f / 128.0f) + 1.1920929e-07f);
  float n0 = x0 * rn, n1 = x1 * rn;
  float partner = __shfl_xor(n0, 16);
  if (lane < 32) {
    int i = lane & 15;
    float c = ctab[s * 16 + i], sn = stab[s * 16 + i];
    n0 = (lane < 16) ? (n0 * c + partner * sn) : (n0 * c - partner * sn);
  }
  if (isQ) { float g = qgain[hh]; n0 *= g; n1 *= g; }
  dst[lane] = f2h_bits(n0);
  dst[lane + 64] = f2h_bits(n1);
}

// ---------------- V transpose: qkv v-block -> Vt[b][kvh][d][s] ----------------
__global__ __launch_bounds__(256) void vtrans(const unsigned short* __restrict__ qkv,
                                              unsigned short* __restrict__ Vt) {
  int idx = blockIdx.x * 256 + threadIdx.x;
  int d = idx & 127;
  int sc = (idx >> 7) & 255;
  int kvh = (idx >> 15) & 3;
  int b = idx >> 17;
  u16x8 v;
#pragma unroll
  for (int j = 0; j < 8; ++j)
    v[j] = qkv[((long)(b * S_LEN + sc * 8 + j)) * 3072 + 2560 + kvh * HD + d];
  *reinterpret_cast<u16x8*>(Vt + (((long)(b * NKV + kvh)) * HD + d) * S_LEN + sc * 8) = v;
}

// ---------------- causal GQA attention: 32q/wave, conflict-free LDS ----------------
#define ATT_C3 ((float)(0.08838834764831845 * (2.0 / 30.0) * 1.4426950408889634))
#define ATT_C4 ((float)(30.0 * 1.4426950408889634))
#define ATT_C5 ((float)(60.0 * 1.4426950408889634))
#define ATT_THR ((float)(8.0 * 1.4426950408889634))

__global__ __launch_bounds__(256, 2) void attn(const unsigned short* __restrict__ Qb,
                                               const unsigned short* __restrict__ Kb,
                                               const unsigned short* __restrict__ Vt,
                                               unsigned short* __restrict__ Yb) {
  // K tile: 32 physical rows (= MFMA A-rows; kv permuted at staging) x 128 hd, chunk^=(rho&7)
  // V tile: 128 d-rows x 32 kv, chunk^=((d>>1)&3). Both double-buffered. 32 KB total.
  __shared__ unsigned short Klds[2][32 * 128];
  __shared__ unsigned short Vlds[2][128 * 32];
  const int tid = threadIdx.x, wid = tid >> 6, lane = tid & 63;
  const int bid = blockIdx.x;
  // blocks bid and bid+256 land on the same CU: make their qb sum to 15 -> uniform CU work
  const int qb = (bid >> 8) ? (15 - (bid & 15)) : (bid & 15);
  const int h = (bid >> 4) & 15, b = bid >> 8;
  const int kvh = h >> 2;
  const int q0w = qb * 128 + wid * 32;
  const int rlo = lane & 15, hi = lane >> 4;
  const unsigned short* Qp = Qb + (((long)(b * NH + h)) * S_LEN + q0w) * HD;
  const unsigned short* Kp = Kb + ((long)(b * NKV + kvh)) * S_LEN * HD;
  const unsigned short* Vp = Vt + ((long)(b * NKV + kvh)) * HD * S_LEN;
  // Q B-operand fragments for both 16-row subtiles (resident all kernel)
  f16x8 bqA[4], bqB[4];
#pragma unroll
  for (int dk = 0; dk < 4; ++dk) {
    bqA[dk] = ld8(Qp + rlo * HD + dk * 32 + hi * 8);
    bqB[dk] = ld8(Qp + (16 + rlo) * HD + dk * 32 + hi * 8);
  }
  // staging constants (dest linear per gload_lds; permutation+swizzle folded into SRC)
  const int kRho0 = wid * 8 + (lane >> 4);          // K call q: rho = wid*8 + q*4 + (lane>>4)
  const int vD0 = wid * 32 + (lane >> 2);           // V call q: d = wid*32 + q*16 + (lane>>2)
  const int kx = rlo & 7;                           // K read chunk XOR
  const int vx = (rlo >> 1) & 3;                    // V read chunk XOR
  f32x4 accA[8] = {}, accB[8] = {};
  float m2cA = ATT_C4 + 128.0f, m2cB = ATT_C4 + 128.0f;
  float lA = 0.0f, lB = 0.0f;
  const int nt = 4 * qb + 4;
  const int tlast = 4 * qb + wid;  // this wave computes t <= tlast; masks at t == tlast

  auto stage = [&](int bf, int k0) {
#pragma unroll
    for (int q = 0; q < 2; ++q) {
      int rho = kRho0 + q * 4;
      int kv = 8 * ((rho >> 2) & 3) + (rho & 3) + 4 * (rho >> 4);  // A-row -> kv permutation
      int clog = (lane & 15) ^ (rho & 7);
      gload_lds16(Kp + (long)(k0 + kv) * HD + clog * 8, &Klds[bf][(wid * 2 + q) * 512]);
      int d = vD0 + q * 16;
      int vcl = (lane & 3) ^ ((d >> 1) & 3);
      gload_lds16(Vp + (long)d * S_LEN + k0 + vcl * 8, &Vlds[bf][(wid * 2 + q) * 512]);
    }
  };

  // softmax for one subtile; returns packed P fragment
  auto softmax = [&](const f32x4& s0, const f32x4& s1, float& m2c, float& l_run,
                     f32x4* accO, int qrel, bool domask) -> f16x8 {
    float ea[8];
#pragma unroll
    for (int j = 0; j < 8; ++j) {
      float sc = (j < 4) ? s0[j] : s1[j - 4];
      float u = __builtin_amdgcn_exp2f(sc * ATT_C3);
      float rr = __builtin_amdgcn_rcpf(u + 1.0f);
      ea[j] = fmaf(-ATT_C5, rr, m2c);
    }
    if (domask) {
#pragma unroll
      for (int j = 0; j < 8; ++j)
        ea[j] = (8 * hi + j > qrel) ? -1e30f : ea[j];
    }
    float pm = ea[0];
#pragma unroll
    for (int j = 1; j < 8; ++j) pm = fmaxf(pm, ea[j]);
    if (!__all(pm <= ATT_THR)) {
      float red = fmaxf(pm, __shfl_xor(pm, 16));
      red = fmaxf(red, __shfl_xor(red, 32));
      red = fmaxf(red, 0.0f);
      m2c -= red;
      float f = __builtin_amdgcn_exp2f(-red);
      l_run *= f;
#pragma unroll
      for (int dt = 0; dt < 8; ++dt) accO[dt] *= f;
#pragma unroll
      for (int j = 0; j < 8; ++j) ea[j] -= red;
    }
    float p[8];
#pragma unroll
    for (int j = 0; j < 8; ++j) p[j] = __builtin_amdgcn_exp2f(ea[j]);
    l_run += ((p[0] + p[1]) + (p[2] + p[3])) + ((p[4] + p[5]) + (p[6] + p[7]));
    u32x4 pk;
    pk.x = __builtin_bit_cast(unsigned int, __builtin_amdgcn_cvt_pkrtz(p[0], p[1]));
    pk.y = __builtin_bit_cast(unsigned int, __builtin_amdgcn_cvt_pkrtz(p[2], p[3]));
    pk.z = __builtin_bit_cast(unsigned int, __builtin_amdgcn_cvt_pkrtz(p[4], p[5]));
    pk.w = __builtin_bit_cast(unsigned int, __builtin_amdgcn_cvt_pkrtz(p[6], p[7]));
    return __builtin_bit_cast(f16x8, pk);
  };

  stage(0, 0);
  __syncthreads();
  int buf = 0;
  for (int t = 0; t < nt; ++t) {
    if (t + 1 < nt) stage(buf ^ 1, (t + 1) * 32);
    if (t <= tlast) {
      // --- QK^T: K frags shared by both subtiles
      f32x4 s0A = {0.f, 0.f, 0.f, 0.f}, s1A = s0A, s0B = s0A, s1B = s0A;
      __builtin_amdgcn_s_setprio(1);
#pragma unroll
      for (int dk = 0; dk < 4; ++dk) {
        int cp = ((dk * 4 + hi) ^ kx) * 8;
        f16x8 a0 = ld8(&Klds[buf][rlo * 128 + cp]);
        f16x8 a1 = ld8(&Klds[buf][(16 + rlo) * 128 + cp]);
        s0A = __builtin_amdgcn_mfma_f32_16x16x32_f16(a0, bqA[dk], s0A, 0, 0, 0);
        s1A = __builtin_amdgcn_mfma_f32_16x16x32_f16(a1, bqA[dk], s1A, 0, 0, 0);
        s0B = __builtin_amdgcn_mfma_f32_16x16x32_f16(a0, bqB[dk], s0B, 0, 0, 0);
        s1B = __builtin_amdgcn_mfma_f32_16x16x32_f16(a1, bqB[dk], s1B, 0, 0, 0);
      }
      __builtin_amdgcn_s_setprio(0);
      const bool domask = (t == tlast);
      f16x8 bpA = softmax(s0A, s1A, m2cA, lA, accA, rlo, domask);
      f16x8 bpB = softmax(s0B, s1B, m2cB, lB, accB, 16 + rlo, domask);
      // --- PV: V frags shared by both subtiles
      __builtin_amdgcn_s_setprio(1);
#pragma unroll
      for (int g = 0; g < 2; ++g) {
        f16x8 av[4];
#pragma unroll
        for (int i = 0; i < 4; ++i) {
          int d = (g * 4 + i) * 16 + rlo;
          av[i] = ld8(&Vlds[buf][d * 32 + ((hi ^ vx) * 8)]);
        }
#pragma unroll
        for (int i = 0; i < 4; ++i) {
          accA[g * 4 + i] = __builtin_amdgcn_mfma_f32_16x16x32_f16(av[i], bpA, accA[g * 4 + i], 0, 0, 0);
          accB[g * 4 + i] = __builtin_amdgcn_mfma_f32_16x16x32_f16(av[i], bpB, accB[g * 4 + i], 0, 0, 0);
        }
      }
      __builtin_amdgcn_s_setprio(0);
    }
    __syncthreads();  // drains vmcnt (stage of t+1 done) + all reads of buf done
    buf ^= 1;
  }
  // finalize both subtiles
  float l1 = lA + __shfl_xor(lA, 16); l1 += __shfl_xor(l1, 32);
  float l2 = lB + __shfl_xor(lB, 16); l2 += __shfl_xor(l2, 32);
  float invA2 = 1.0f / l1, invB2 = 1.0f / l2;
  unsigned short* ypA = Yb + ((long)(b * S_LEN + q0w + rlo)) * DIM + h * HD + 4 * hi;
  unsigned short* ypB = Yb + ((long)(b * S_LEN + q0w + 16 + rlo)) * DIM + h * HD + 4 * hi;
#pragma unroll
  for (int dt = 0; dt < 8; ++dt) {
    u16x4 oA, oB;
#pragma unroll
    for (int r = 0; r < 4; ++r) {
      oA[r] = f2h_bits(accA[dt][r] * invA2);
      oB[r] = f2h_bits(accB[dt][r] * invB2);
    }
    *reinterpret_cast<u16x4*>(ypA + dt * 16) = oA;
    *reinterpret_cast<u16x4*>(ypB + dt * 16) = oB;
  }
}

extern "C" void kernel_launch(void* const* d_in, const int* in_sizes, int n_in,
                              void* d_out, int out_size, void* d_ws, size_t ws_size,
                              hipStream_t stream) {
  const float* x = (const float*)d_in[0];
  const float* Wq = (const float*)d_in[1];
  const float* Wk = (const float*)d_in[2];
  const float* Wv = (const float*)d_in[3];
  const float* Wp = (const float*)d_in[4];
  const float* qg = (const float*)d_in[5];
  float* out = (float*)d_out;

  char* ws = (char*)d_ws;
  size_t off = 0;
  auto alloc = [&](size_t bytes) {
    char* p = ws + off;
    off += (bytes + 255) & ~(size_t)255;
    return p;
  };
  unsigned short* xb   = (unsigned short*)alloc(8388608ull * 2);
  unsigned short* wqkv = (unsigned short*)alloc(6291456ull * 2);
  unsigned short* wpj  = (unsigned short*)alloc(4194304ull * 2);
  unsigned short* qkv  = (unsigned short*)alloc(4096ull * 3072 * 2);
  unsigned short* Qb   = (unsigned short*)alloc(8388608ull * 2);
  unsigned short* Kb   = (unsigned short*)alloc(2097152ull * 2);
  unsigned short* Vt   = (unsigned short*)alloc(2097152ull * 2);
  unsigned short* Yb   = (unsigned short*)alloc(8388608ull * 2);
  float* ctab = (float*)alloc(32768ull * 4);
  float* stab = (float*)alloc(32768ull * 4);

  auto cvt = [&](const float* src, unsigned short* dst, int n) {
    int n4 = n / 4;
    cvt_f32_f16<<<(n4 + 255) / 256, 256, 0, stream>>>(src, dst, n4);
  };
  cvt(x, xb, 8388608);
  cvt(Wq, wqkv, 4194304);
  cvt(Wk, wqkv + 4194304, 1048576);
  cvt(Wv, wqkv + 5242880, 1048576);
  cvt(Wp, wpj, 4194304);
  rope_tables<<<128, 256, 0, stream>>>(ctab, stab);

  gemm_bt<unsigned short><<<dim3(32, 24), 256, 0, stream>>>(xb, wqkv, qkv, 2048, 3072);

  qknorm_rope<<<(BATCH * S_LEN * (NH + NKV)) / 4, 256, 0, stream>>>(qkv, ctab, stab, qg, Qb, Kb);
  vtrans<<<(BATCH * NKV * HD * (S_LEN / 8)) / 256, 256, 0, stream>>>(qkv, Vt);

  attn<<<512, 256, 0, stream>>>(Qb, Kb, Vt, Yb);

  gemm_bt<float><<<dim3(32, 16), 256, 0, stream>>>(Yb, wpj, out, 2048, 2048);
}

// Round 5
// 253.824 us; speedup vs baseline: 2.5572x; 1.0637x over previous
//
#include <hip/hip_runtime.h>
#include <type_traits>

#define BATCH 2
#define S_LEN 2048
#define DIM 2048
#define NH 16
#define NKV 4
#define HD 128

typedef _Float16 f16x8 __attribute__((ext_vector_type(8)));
typedef float f32x4 __attribute__((ext_vector_type(4)));
typedef unsigned int u32x4 __attribute__((ext_vector_type(4)));
typedef unsigned short u16x4 __attribute__((ext_vector_type(4)));
typedef unsigned short u16x8 __attribute__((ext_vector_type(8)));

__device__ __forceinline__ unsigned short f2h_bits(float f) {
  _Float16 h = (_Float16)f;
  return __builtin_bit_cast(unsigned short, h);
}
__device__ __forceinline__ float h2f(unsigned short u) {
  return (float)__builtin_bit_cast(_Float16, u);
}
__device__ __forceinline__ f16x8 ld8(const unsigned short* p) {
  u32x4 v = *reinterpret_cast<const u32x4*>(p);
  return __builtin_bit_cast(f16x8, v);
}
__device__ __forceinline__ void gload_lds16(const unsigned short* g, unsigned short* l) {
  __builtin_amdgcn_global_load_lds(
      (const __attribute__((address_space(1))) unsigned int*)g,
      (__attribute__((address_space(3))) unsigned int*)l, 16, 0, 0);
}

// ---------------- fp32 -> fp16 convert ----------------
__global__ __launch_bounds__(256) void cvt_f32_f16(const float* __restrict__ in,
                                                   unsigned short* __restrict__ out, int n4) {
  int i = blockIdx.x * 256 + threadIdx.x;
  if (i >= n4) return;
  f32x4 v = *reinterpret_cast<const f32x4*>(in + (long)i * 4);
  u16x4 o;
  o.x = f2h_bits(v.x); o.y = f2h_bits(v.y); o.z = f2h_bits(v.z); o.w = f2h_bits(v.w);
  *reinterpret_cast<u16x4*>(out + (long)i * 4) = o;
}

// ---------------- RoPE tables (fp32) ----------------
__global__ __launch_bounds__(256) void rope_tables(float* __restrict__ c, float* __restrict__ s) {
  int idx = blockIdx.x * 256 + threadIdx.x;
  if (idx >= S_LEN * 16) return;
  int i = idx & 15, t = idx >> 4;
  float inv = exp2f(-(float)i * (13.287712379549449f / 16.0f));
  float f = (float)t * inv;
  c[idx] = cosf(f);
  s[idx] = sinf(f);
}

// ================= 8-phase 256-row GEMM: C[m][n] = sum_k A[m][k]*B[n][k] =================
// BM=256, BN=64*NREP, BK=64. 512 thr = 8 waves (2M x 4N). Per-wave out 128 x 16*NREP.
// LDS per slot: A[kk][sigma 0..255][32] (sigma = quarter-permuted row), B[kk][r][32],
// chunk swizzle pc = hi ^ (row&3)  (2-way residual alias = free, m136).
// Schedule per K-tile: 4 phases {counted vmcnt; raw s_barrier; stage 1 region of t+1;
// ds_read frags; setprio(1); 4*NREP MFMA; setprio(0)}. vmcnt never 0 in steady loop.
#define VMWAIT(n) asm volatile("s_waitcnt vmcnt(" #n ")" ::: "memory")

template <int NREP, typename OUT>
__global__ __launch_bounds__(512, 2) void gemm8p(const unsigned short* __restrict__ A,
                                                 const unsigned short* __restrict__ B,
                                                 OUT* __restrict__ C, int K, int ldc) {
  constexpr int BN = 64 * NREP;
  constexpr int BSH = BN * 32;         // shorts per B kk-block
  constexpr int TS = 16384 + BN * 64;  // shorts per slot
  __shared__ unsigned short lds[2][TS];
  const int tid = threadIdx.x, lane = tid & 63;
  const int wm = tid >> 8, wn = (tid >> 6) & 3;
  const int rlo = lane & 15, hi = lane >> 4;
  const int m0 = blockIdx.x * 256, n0 = blockIdx.y * BN;
  const int NT = K >> 6;
  const int brow = wn * (16 * NREP);

  const int sA_s = tid >> 2;  // sigma offset within an A stage call
  const int pc2 = tid & 3;

  // sigma -> tile row (quarter permutation: sig[0,64)=rows 0-63, [64,128)=128-191,
  // [128,192)=64-127, [192,256)=192-255); sig&3 == row&3 everywhere.
  auto aRow = [&](int sig) { return (sig & 63) + ((sig >> 6) & 1) * 128 + (sig >> 7) * 64; };

  auto stageA = [&](int slot, int k0, int kk, int sig0) {
    int sig = sig0 + sA_s;
    int r = aRow(sig);
    int lc2 = pc2 ^ (sig & 3);
    gload_lds16(A + (long)(m0 + r) * K + k0 + kk * 32 + lc2 * 8,
                &lds[slot][kk * 8192 + sig0 * 32 + tid * 8]);
  };
  auto stageB = [&](int slot, int k0, int kk) {
#pragma unroll
    for (int q = 0; q < NREP / 2; ++q) {
      int idx = tid + q * 512;
      int r = idx >> 2;
      int lc2 = (idx & 3) ^ (r & 3);
      gload_lds16(B + (long)(n0 + r) * K + k0 + kk * 32 + lc2 * 8,
                  &lds[slot][16384 + kk * BSH + idx * 8]);
    }
  };

  f32x4 acc[8][NREP] = {};

  // prologue: stage H(0) in FIFO order S0,S1,S2,S3
  stageA(0, 0, 0, 0);   stageB(0, 0, 0);   // S0: A kk0 sig[0,128) + B kk0
  stageA(0, 0, 1, 0);   stageB(0, 0, 1);   // S1: A kk1 sig[0,128) + B kk1
  stageA(0, 0, 0, 128);                    // S2: A kk0 sig[128,256)
  stageA(0, 0, 1, 128);                    // S3: A kk1 sig[128,256)

#define GPHASE(MH, KK, VMS, VML, ...)                                                 \
  {                                                                                   \
    if (pf) { VMWAIT(VMS); } else { VMWAIT(VML); }                                    \
    __builtin_amdgcn_s_barrier();                                                     \
    asm volatile("" ::: "memory");                                                    \
    if (pf) { __VA_ARGS__; }                                                          \
    f16x8 af[4], bf[NREP];                                                            \
    _Pragma("unroll")                                                                 \
    for (int i = 0; i < 4; ++i) {                                                     \
      int ms = MH * 4 + i;                                                            \
      int sig = (ms & 3) * 16 + rlo + wm * 64 + (ms >> 2) * 128;                      \
      af[i] = ld8(&As[KK * 8192 + sig * 32 + ((hi ^ (sig & 3)) * 8)]);                \
    }                                                                                 \
    _Pragma("unroll")                                                                 \
    for (int j = 0; j < NREP; ++j) {                                                  \
      int r = brow + j * 16 + rlo;                                                    \
      bf[j] = ld8(&Bs[KK * BSH + r * 32 + ((hi ^ (r & 3)) * 8)]);                     \
    }                                                                                 \
    __builtin_amdgcn_s_setprio(1);                                                    \
    _Pragma("unroll")                                                                 \
    for (int i = 0; i < 4; ++i)                                                       \
      _Pragma("unroll")                                                               \
      for (int j = 0; j < NREP; ++j)                                                  \
        acc[MH * 4 + i][j] =                                                          \
            __builtin_amdgcn_mfma_f32_16x16x32_f16(af[i], bf[j], acc[MH * 4 + i][j],  \
                                                   0, 0, 0);                          \
    __builtin_amdgcn_s_setprio(0);                                                    \
  }

  for (int t = 0; t < NT; ++t) {
    const int slot = t & 1, nslot = slot ^ 1;
    const int k0n = (t + 1) << 6;
    const bool pf = (t + 1) < NT;
    const unsigned short* As = &lds[slot][0];
    const unsigned short* Bs = &lds[slot][16384];
    if constexpr (NREP == 4) {
      GPHASE(0, 0, 5, 5, stageA(nslot, k0n, 0, 0); stageB(nslot, k0n, 0))
      GPHASE(0, 1, 5, 2, stageA(nslot, k0n, 1, 0); stageB(nslot, k0n, 1))
      GPHASE(1, 0, 7, 1, stageA(nslot, k0n, 0, 128))
      GPHASE(1, 1, 7, 0, stageA(nslot, k0n, 1, 128))
    } else {
      GPHASE(0, 0, 4, 4, stageA(nslot, k0n, 0, 0); stageB(nslot, k0n, 0))
      GPHASE(0, 1, 4, 2, stageA(nslot, k0n, 1, 0); stageB(nslot, k0n, 1))
      GPHASE(1, 0, 5, 1, stageA(nslot, k0n, 0, 128))
      GPHASE(1, 1, 5, 0, stageA(nslot, k0n, 1, 128))
    }
  }
#undef GPHASE

  // epilogue
#pragma unroll
  for (int ms = 0; ms < 8; ++ms)
#pragma unroll
    for (int j = 0; j < NREP; ++j) {
      int row = m0 + wm * 128 + ms * 16 + hi * 4;
      int col = n0 + brow + j * 16 + rlo;
#pragma unroll
      for (int r = 0; r < 4; ++r) {
        float v = acc[ms][j][r];
        if constexpr (std::is_same<OUT, float>::value)
          C[(long)(row + r) * ldc + col] = v;
        else
          C[(long)(row + r) * ldc + col] = f2h_bits(v);
      }
    }
}

// ---------------- RMSNorm + RoPE + gain, scatter into Q/K layouts ----------------
__global__ __launch_bounds__(256) void qknorm_rope(const unsigned short* __restrict__ qkv,
                                                   const float* __restrict__ ctab,
                                                   const float* __restrict__ stab,
                                                   const float* __restrict__ qgain,
                                                   unsigned short* __restrict__ Qb,
                                                   unsigned short* __restrict__ Kb) {
  const int lane = threadIdx.x & 63;
  const int row = blockIdx.x * 4 + (threadIdx.x >> 6);
  const int NQROWS = BATCH * S_LEN * NH;
  const unsigned short* src;
  unsigned short* dst;
  int m, hh;
  bool isQ;
  if (row < NQROWS) {
    m = row >> 4; hh = row & 15;
    src = qkv + (long)m * 3072 + hh * HD;
    int b = m >> 11, s = m & (S_LEN - 1);
    dst = Qb + (((long)(b * NH + hh)) * S_LEN + s) * HD;
    isQ = true;
  } else {
    int rk = row - NQROWS;
    m = rk >> 2; hh = rk & 3;
    src = qkv + (long)m * 3072 + 2048 + hh * HD;
    int b = m >> 11, s = m & (S_LEN - 1);
    dst = Kb + (((long)(b * NKV + hh)) * S_LEN + s) * HD;
    isQ = false;
  }
  const int s = m & (S_LEN - 1);
  float x0 = h2f(src[lane]);
  float x1 = h2f(src[lane + 64]);
  float ss = x0 * x0 + x1 * x1;
  ss += __shfl_xor(ss, 1); ss += __shfl_xor(ss, 2); ss += __shfl_xor(ss, 4);
  ss += __shfl_xor(ss, 8); ss += __shfl_xor(ss, 16); ss += __shfl_xor(ss, 32);
  float rn = rsqrtf(ss * (1.0f / 128.0f) + 1.1920929e-07f);
  float n0 = x0 * rn, n1 = x1 * rn;
  float partner = __shfl_xor(n0, 16);
  if (lane < 32) {
    int i = lane & 15;
    float c = ctab[s * 16 + i], sn = stab[s * 16 + i];
    n0 = (lane < 16) ? (n0 * c + partner * sn) : (n0 * c - partner * sn);
  }
  if (isQ) { float g = qgain[hh]; n0 *= g; n1 *= g; }
  dst[lane] = f2h_bits(n0);
  dst[lane + 64] = f2h_bits(n1);
}

// ---------------- V transpose: qkv v-block -> Vt[b][kvh][d][s] ----------------
__global__ __launch_bounds__(256) void vtrans(const unsigned short* __restrict__ qkv,
                                              unsigned short* __restrict__ Vt) {
  int idx = blockIdx.x * 256 + threadIdx.x;
  int d = idx & 127;
  int sc = (idx >> 7) & 255;
  int kvh = (idx >> 15) & 3;
  int b = idx >> 17;
  u16x8 v;
#pragma unroll
  for (int j = 0; j < 8; ++j)
    v[j] = qkv[((long)(b * S_LEN + sc * 8 + j)) * 3072 + 2560 + kvh * HD + d];
  *reinterpret_cast<u16x8*>(Vt + (((long)(b * NKV + kvh)) * HD + d) * S_LEN + sc * 8) = v;
}

// ---------------- causal GQA attention: 32q/wave, conflict-free LDS ----------------
#define ATT_C3 ((float)(0.08838834764831845 * (2.0 / 30.0) * 1.4426950408889634))
#define ATT_C4 ((float)(30.0 * 1.4426950408889634))
#define ATT_C5 ((float)(60.0 * 1.4426950408889634))
#define ATT_THR ((float)(8.0 * 1.4426950408889634))

__global__ __launch_bounds__(256, 2) void attn(const unsigned short* __restrict__ Qb,
                                               const unsigned short* __restrict__ Kb,
                                               const unsigned short* __restrict__ Vt,
                                               unsigned short* __restrict__ Yb) {
  __shared__ unsigned short Klds[2][32 * 128];
  __shared__ unsigned short Vlds[2][128 * 32];
  const int tid = threadIdx.x, wid = tid >> 6, lane = tid & 63;
  const int bid = blockIdx.x;
  const int qb = (bid >> 8) ? (15 - (bid & 15)) : (bid & 15);
  const int h = (bid >> 4) & 15, b = bid >> 8;
  const int kvh = h >> 2;
  const int q0w = qb * 128 + wid * 32;
  const int rlo = lane & 15, hi = lane >> 4;
  const unsigned short* Qp = Qb + (((long)(b * NH + h)) * S_LEN + q0w) * HD;
  const unsigned short* Kp = Kb + ((long)(b * NKV + kvh)) * S_LEN * HD;
  const unsigned short* Vp = Vt + ((long)(b * NKV + kvh)) * HD * S_LEN;
  f16x8 bqA[4], bqB[4];
#pragma unroll
  for (int dk = 0; dk < 4; ++dk) {
    bqA[dk] = ld8(Qp + rlo * HD + dk * 32 + hi * 8);
    bqB[dk] = ld8(Qp + (16 + rlo) * HD + dk * 32 + hi * 8);
  }
  const int kRho0 = wid * 8 + (lane >> 4);
  const int vD0 = wid * 32 + (lane >> 2);
  const int kx = rlo & 7;
  const int vx = (rlo >> 1) & 3;
  f32x4 accA[8] = {}, accB[8] = {};
  float m2cA = ATT_C4 + 128.0f, m2cB = ATT_C4 + 128.0f;
  float lA = 0.0f, lB = 0.0f;
  const int nt = 4 * qb + 4;
  const int tlast = 4 * qb + wid;

  auto stage = [&](int bf, int k0) {
#pragma unroll
    for (int q = 0; q < 2; ++q) {
      int rho = kRho0 + q * 4;
      int kv = 8 * ((rho >> 2) & 3) + (rho & 3) + 4 * (rho >> 4);
      int clog = (lane & 15) ^ (rho & 7);
      gload_lds16(Kp + (long)(k0 + kv) * HD + clog * 8, &Klds[bf][(wid * 2 + q) * 512]);
      int d = vD0 + q * 16;
      int vcl = (lane & 3) ^ ((d >> 1) & 3);
      gload_lds16(Vp + (long)d * S_LEN + k0 + vcl * 8, &Vlds[bf][(wid * 2 + q) * 512]);
    }
  };

  auto softmax = [&](const f32x4& s0, const f32x4& s1, float& m2c, float& l_run,
                     f32x4* accO, int qrel, bool domask) -> f16x8 {
    float ea[8];
#pragma unroll
    for (int j = 0; j < 8; ++j) {
      float sc = (j < 4) ? s0[j] : s1[j - 4];
      float u = __builtin_amdgcn_exp2f(sc * ATT_C3);
      float rr = __builtin_amdgcn_rcpf(u + 1.0f);
      ea[j] = fmaf(-ATT_C5, rr, m2c);
    }
    if (domask) {
#pragma unroll
      for (int j = 0; j < 8; ++j)
        ea[j] = (8 * hi + j > qrel) ? -1e30f : ea[j];
    }
    float pm = ea[0];
#pragma unroll
    for (int j = 1; j < 8; ++j) pm = fmaxf(pm, ea[j]);
    if (!__all(pm <= ATT_THR)) {
      float red = fmaxf(pm, __shfl_xor(pm, 16));
      red = fmaxf(red, __shfl_xor(red, 32));
      red = fmaxf(red, 0.0f);
      m2c -= red;
      float f = __builtin_amdgcn_exp2f(-red);
      l_run *= f;
#pragma unroll
      for (int dt = 0; dt < 8; ++dt) accO[dt] *= f;
#pragma unroll
      for (int j = 0; j < 8; ++j) ea[j] -= red;
    }
    float p[8];
#pragma unroll
    for (int j = 0; j < 8; ++j) p[j] = __builtin_amdgcn_exp2f(ea[j]);
    l_run += ((p[0] + p[1]) + (p[2] + p[3])) + ((p[4] + p[5]) + (p[6] + p[7]));
    u32x4 pk;
    pk.x = __builtin_bit_cast(unsigned int, __builtin_amdgcn_cvt_pkrtz(p[0], p[1]));
    pk.y = __builtin_bit_cast(unsigned int, __builtin_amdgcn_cvt_pkrtz(p[2], p[3]));
    pk.z = __builtin_bit_cast(unsigned int, __builtin_amdgcn_cvt_pkrtz(p[4], p[5]));
    pk.w = __builtin_bit_cast(unsigned int, __builtin_amdgcn_cvt_pkrtz(p[6], p[7]));
    return __builtin_bit_cast(f16x8, pk);
  };

  stage(0, 0);
  __syncthreads();
  int buf = 0;
  for (int t = 0; t < nt; ++t) {
    if (t + 1 < nt) stage(buf ^ 1, (t + 1) * 32);
    if (t <= tlast) {
      f32x4 s0A = {0.f, 0.f, 0.f, 0.f}, s1A = s0A, s0B = s0A, s1B = s0A;
      __builtin_amdgcn_s_setprio(1);
#pragma unroll
      for (int dk = 0; dk < 4; ++dk) {
        int cp = ((dk * 4 + hi) ^ kx) * 8;
        f16x8 a0 = ld8(&Klds[buf][rlo * 128 + cp]);
        f16x8 a1 = ld8(&Klds[buf][(16 + rlo) * 128 + cp]);
        s0A = __builtin_amdgcn_mfma_f32_16x16x32_f16(a0, bqA[dk], s0A, 0, 0, 0);
        s1A = __builtin_amdgcn_mfma_f32_16x16x32_f16(a1, bqA[dk], s1A, 0, 0, 0);
        s0B = __builtin_amdgcn_mfma_f32_16x16x32_f16(a0, bqB[dk], s0B, 0, 0, 0);
        s1B = __builtin_amdgcn_mfma_f32_16x16x32_f16(a1, bqB[dk], s1B, 0, 0, 0);
      }
      __builtin_amdgcn_s_setprio(0);
      const bool domask = (t == tlast);
      f16x8 bpA = softmax(s0A, s1A, m2cA, lA, accA, rlo, domask);
      f16x8 bpB = softmax(s0B, s1B, m2cB, lB, accB, 16 + rlo, domask);
      __builtin_amdgcn_s_setprio(1);
#pragma unroll
      for (int g = 0; g < 2; ++g) {
        f16x8 av[4];
#pragma unroll
        for (int i = 0; i < 4; ++i) {
          int d = (g * 4 + i) * 16 + rlo;
          av[i] = ld8(&Vlds[buf][d * 32 + ((hi ^ vx) * 8)]);
        }
#pragma unroll
        for (int i = 0; i < 4; ++i) {
          accA[g * 4 + i] = __builtin_amdgcn_mfma_f32_16x16x32_f16(av[i], bpA, accA[g * 4 + i], 0, 0, 0);
          accB[g * 4 + i] = __builtin_amdgcn_mfma_f32_16x16x32_f16(av[i], bpB, accB[g * 4 + i], 0, 0, 0);
        }
      }
      __builtin_amdgcn_s_setprio(0);
    }
    __syncthreads();
    buf ^= 1;
  }
  float l1 = lA + __shfl_xor(lA, 16); l1 += __shfl_xor(l1, 32);
  float l2 = lB + __shfl_xor(lB, 16); l2 += __shfl_xor(l2, 32);
  float invA2 = 1.0f / l1, invB2 = 1.0f / l2;
  unsigned short* ypA = Yb + ((long)(b * S_LEN + q0w + rlo)) * DIM + h * HD + 4 * hi;
  unsigned short* ypB = Yb + ((long)(b * S_LEN + q0w + 16 + rlo)) * DIM + h * HD + 4 * hi;
#pragma unroll
  for (int dt = 0; dt < 8; ++dt) {
    u16x4 oA, oB;
#pragma unroll
    for (int r = 0; r < 4; ++r) {
      oA[r] = f2h_bits(accA[dt][r] * invA2);
      oB[r] = f2h_bits(accB[dt][r] * invB2);
    }
    *reinterpret_cast<u16x4*>(ypA + dt * 16) = oA;
    *reinterpret_cast<u16x4*>(ypB + dt * 16) = oB;
  }
}

extern "C" void kernel_launch(void* const* d_in, const int* in_sizes, int n_in,
                              void* d_out, int out_size, void* d_ws, size_t ws_size,
                              hipStream_t stream) {
  const float* x = (const float*)d_in[0];
  const float* Wq = (const float*)d_in[1];
  const float* Wk = (const float*)d_in[2];
  const float* Wv = (const float*)d_in[3];
  const float* Wp = (const float*)d_in[4];
  const float* qg = (const float*)d_in[5];
  float* out = (float*)d_out;

  char* ws = (char*)d_ws;
  size_t off = 0;
  auto alloc = [&](size_t bytes) {
    char* p = ws + off;
    off += (bytes + 255) & ~(size_t)255;
    return p;
  };
  unsigned short* xb   = (unsigned short*)alloc(8388608ull * 2);
  unsigned short* wqkv = (unsigned short*)alloc(6291456ull * 2);
  unsigned short* wpj  = (unsigned short*)alloc(4194304ull * 2);
  unsigned short* qkv  = (unsigned short*)alloc(4096ull * 3072 * 2);
  unsigned short* Qb   = (unsigned short*)alloc(8388608ull * 2);
  unsigned short* Kb   = (unsigned short*)alloc(2097152ull * 2);
  unsigned short* Vt   = (unsigned short*)alloc(2097152ull * 2);
  unsigned short* Yb   = (unsigned short*)alloc(8388608ull * 2);
  float* ctab = (float*)alloc(32768ull * 4);
  float* stab = (float*)alloc(32768ull * 4);

  auto cvt = [&](const float* src, unsigned short* dst, int n) {
    int n4 = n / 4;
    cvt_f32_f16<<<(n4 + 255) / 256, 256, 0, stream>>>(src, dst, n4);
  };
  cvt(x, xb, 8388608);
  cvt(Wq, wqkv, 4194304);
  cvt(Wk, wqkv + 4194304, 1048576);
  cvt(Wv, wqkv + 5242880, 1048576);
  cvt(Wp, wpj, 4194304);
  rope_tables<<<128, 256, 0, stream>>>(ctab, stab);

  // qkv = x @ [Wq;Wk;Wv]^T : M=4096 N=3072 K=2048  (256x256 tiles)
  gemm8p<4, unsigned short><<<dim3(16, 12), 512, 0, stream>>>(xb, wqkv, qkv, 2048, 3072);

  qknorm_rope<<<(BATCH * S_LEN * (NH + NKV)) / 4, 256, 0, stream>>>(qkv, ctab, stab, qg, Qb, Kb);
  vtrans<<<(BATCH * NKV * HD * (S_LEN / 8)) / 256, 256, 0, stream>>>(qkv, Vt);

  attn<<<512, 256, 0, stream>>>(Qb, Kb, Vt, Yb);

  // out = y @ Wproj^T : M=4096 N=2048 K=2048  (256x128 tiles, full 256-block grid)
  gemm8p<2, float><<<dim3(16, 16), 512, 0, stream>>>(Yb, wpj, out, 2048, 2048);
}

// Round 6
// 243.093 us; speedup vs baseline: 2.6701x; 1.0441x over previous
//
#include <hip/hip_runtime.h>
#include <type_traits>

#define BATCH 2
#define S_LEN 2048
#define DIM 2048
#define NH 16
#define NKV 4
#define HD 128

typedef _Float16 f16x8 __attribute__((ext_vector_type(8)));
typedef float f32x4 __attribute__((ext_vector_type(4)));
typedef unsigned int u32x4 __attribute__((ext_vector_type(4)));
typedef unsigned short u16x4 __attribute__((ext_vector_type(4)));
typedef unsigned short u16x8 __attribute__((ext_vector_type(8)));

__device__ __forceinline__ unsigned short f2h_bits(float f) {
  _Float16 h = (_Float16)f;
  return __builtin_bit_cast(unsigned short, h);
}
__device__ __forceinline__ float h2f(unsigned short u) {
  return (float)__builtin_bit_cast(_Float16, u);
}
__device__ __forceinline__ f16x8 ld8(const unsigned short* p) {
  u32x4 v = *reinterpret_cast<const u32x4*>(p);
  return __builtin_bit_cast(f16x8, v);
}
__device__ __forceinline__ void gload_lds16(const unsigned short* g, unsigned short* l) {
  __builtin_amdgcn_global_load_lds(
      (const __attribute__((address_space(1))) unsigned int*)g,
      (__attribute__((address_space(3))) unsigned int*)l, 16, 0, 0);
}

// ---------------- fp32 -> fp16 convert ----------------
__global__ __launch_bounds__(256) void cvt_f32_f16(const float* __restrict__ in,
                                                   unsigned short* __restrict__ out, int n4) {
  int i = blockIdx.x * 256 + threadIdx.x;
  if (i >= n4) return;
  f32x4 v = *reinterpret_cast<const f32x4*>(in + (long)i * 4);
  u16x4 o;
  o.x = f2h_bits(v.x); o.y = f2h_bits(v.y); o.z = f2h_bits(v.z); o.w = f2h_bits(v.w);
  *reinterpret_cast<u16x4*>(out + (long)i * 4) = o;
}

// ---------------- RoPE tables (fp32) ----------------
__global__ __launch_bounds__(256) void rope_tables(float* __restrict__ c, float* __restrict__ s) {
  int idx = blockIdx.x * 256 + threadIdx.x;
  if (idx >= S_LEN * 16) return;
  int i = idx & 15, t = idx >> 4;
  float inv = exp2f(-(float)i * (13.287712379549449f / 16.0f));
  float f = (float)t * inv;
  c[idx] = cosf(f);
  s[idx] = sinf(f);
}

// ================= 8-phase 256-row GEMM (unchanged from round 5) =================
#define VMWAIT(n) asm volatile("s_waitcnt vmcnt(" #n ")" ::: "memory")

template <int NREP, typename OUT>
__global__ __launch_bounds__(512, 2) void gemm8p(const unsigned short* __restrict__ A,
                                                 const unsigned short* __restrict__ B,
                                                 OUT* __restrict__ C, int K, int ldc) {
  constexpr int BN = 64 * NREP;
  constexpr int BSH = BN * 32;
  constexpr int TS = 16384 + BN * 64;
  __shared__ unsigned short lds[2][TS];
  const int tid = threadIdx.x, lane = tid & 63;
  const int wm = tid >> 8, wn = (tid >> 6) & 3;
  const int rlo = lane & 15, hi = lane >> 4;
  const int m0 = blockIdx.x * 256, n0 = blockIdx.y * BN;
  const int NT = K >> 6;
  const int brow = wn * (16 * NREP);

  const int sA_s = tid >> 2;
  const int pc2 = tid & 3;

  auto aRow = [&](int sig) { return (sig & 63) + ((sig >> 6) & 1) * 128 + (sig >> 7) * 64; };

  auto stageA = [&](int slot, int k0, int kk, int sig0) {
    int sig = sig0 + sA_s;
    int r = aRow(sig);
    int lc2 = pc2 ^ (sig & 3);
    gload_lds16(A + (long)(m0 + r) * K + k0 + kk * 32 + lc2 * 8,
                &lds[slot][kk * 8192 + sig0 * 32 + tid * 8]);
  };
  auto stageB = [&](int slot, int k0, int kk) {
#pragma unroll
    for (int q = 0; q < NREP / 2; ++q) {
      int idx = tid + q * 512;
      int r = idx >> 2;
      int lc2 = (idx & 3) ^ (r & 3);
      gload_lds16(B + (long)(n0 + r) * K + k0 + kk * 32 + lc2 * 8,
                  &lds[slot][16384 + kk * BSH + idx * 8]);
    }
  };

  f32x4 acc[8][NREP] = {};

  stageA(0, 0, 0, 0);   stageB(0, 0, 0);
  stageA(0, 0, 1, 0);   stageB(0, 0, 1);
  stageA(0, 0, 0, 128);
  stageA(0, 0, 1, 128);

#define GPHASE(MH, KK, VMS, VML, ...)                                                 \
  {                                                                                   \
    if (pf) { VMWAIT(VMS); } else { VMWAIT(VML); }                                    \
    __builtin_amdgcn_s_barrier();                                                     \
    asm volatile("" ::: "memory");                                                    \
    if (pf) { __VA_ARGS__; }                                                          \
    f16x8 af[4], bf[NREP];                                                            \
    _Pragma("unroll")                                                                 \
    for (int i = 0; i < 4; ++i) {                                                     \
      int ms = MH * 4 + i;                                                            \
      int sig = (ms & 3) * 16 + rlo + wm * 64 + (ms >> 2) * 128;                      \
      af[i] = ld8(&As[KK * 8192 + sig * 32 + ((hi ^ (sig & 3)) * 8)]);                \
    }                                                                                 \
    _Pragma("unroll")                                                                 \
    for (int j = 0; j < NREP; ++j) {                                                  \
      int r = brow + j * 16 + rlo;                                                    \
      bf[j] = ld8(&Bs[KK * BSH + r * 32 + ((hi ^ (r & 3)) * 8)]);                     \
    }                                                                                 \
    __builtin_amdgcn_s_setprio(1);                                                    \
    _Pragma("unroll")                                                                 \
    for (int i = 0; i < 4; ++i)                                                       \
      _Pragma("unroll")                                                               \
      for (int j = 0; j < NREP; ++j)                                                  \
        acc[MH * 4 + i][j] =                                                          \
            __builtin_amdgcn_mfma_f32_16x16x32_f16(af[i], bf[j], acc[MH * 4 + i][j],  \
                                                   0, 0, 0);                          \
    __builtin_amdgcn_s_setprio(0);                                                    \
  }

  for (int t = 0; t < NT; ++t) {
    const int slot = t & 1, nslot = slot ^ 1;
    const int k0n = (t + 1) << 6;
    const bool pf = (t + 1) < NT;
    const unsigned short* As = &lds[slot][0];
    const unsigned short* Bs = &lds[slot][16384];
    if constexpr (NREP == 4) {
      GPHASE(0, 0, 5, 5, stageA(nslot, k0n, 0, 0); stageB(nslot, k0n, 0))
      GPHASE(0, 1, 5, 2, stageA(nslot, k0n, 1, 0); stageB(nslot, k0n, 1))
      GPHASE(1, 0, 7, 1, stageA(nslot, k0n, 0, 128))
      GPHASE(1, 1, 7, 0, stageA(nslot, k0n, 1, 128))
    } else {
      GPHASE(0, 0, 4, 4, stageA(nslot, k0n, 0, 0); stageB(nslot, k0n, 0))
      GPHASE(0, 1, 4, 2, stageA(nslot, k0n, 1, 0); stageB(nslot, k0n, 1))
      GPHASE(1, 0, 5, 1, stageA(nslot, k0n, 0, 128))
      GPHASE(1, 1, 5, 0, stageA(nslot, k0n, 1, 128))
    }
  }
#undef GPHASE

#pragma unroll
  for (int ms = 0; ms < 8; ++ms)
#pragma unroll
    for (int j = 0; j < NREP; ++j) {
      int row = m0 + wm * 128 + ms * 16 + hi * 4;
      int col = n0 + brow + j * 16 + rlo;
#pragma unroll
      for (int r = 0; r < 4; ++r) {
        float v = acc[ms][j][r];
        if constexpr (std::is_same<OUT, float>::value)
          C[(long)(row + r) * ldc + col] = v;
        else
          C[(long)(row + r) * ldc + col] = f2h_bits(v);
      }
    }
}

// ---------------- RMSNorm + RoPE + gain, scatter into Q/K layouts ----------------
__global__ __launch_bounds__(256) void qknorm_rope(const unsigned short* __restrict__ qkv,
                                                   const float* __restrict__ ctab,
                                                   const float* __restrict__ stab,
                                                   const float* __restrict__ qgain,
                                                   unsigned short* __restrict__ Qb,
                                                   unsigned short* __restrict__ Kb) {
  const int lane = threadIdx.x & 63;
  const int row = blockIdx.x * 4 + (threadIdx.x >> 6);
  const int NQROWS = BATCH * S_LEN * NH;
  const unsigned short* src;
  unsigned short* dst;
  int m, hh;
  bool isQ;
  if (row < NQROWS) {
    m = row >> 4; hh = row & 15;
    src = qkv + (long)m * 3072 + hh * HD;
    int b = m >> 11, s = m & (S_LEN - 1);
    dst = Qb + (((long)(b * NH + hh)) * S_LEN + s) * HD;
    isQ = true;
  } else {
    int rk = row - NQROWS;
    m = rk >> 2; hh = rk & 3;
    src = qkv + (long)m * 3072 + 2048 + hh * HD;
    int b = m >> 11, s = m & (S_LEN - 1);
    dst = Kb + (((long)(b * NKV + hh)) * S_LEN + s) * HD;
    isQ = false;
  }
  const int s = m & (S_LEN - 1);
  float x0 = h2f(src[lane]);
  float x1 = h2f(src[lane + 64]);
  float ss = x0 * x0 + x1 * x1;
  ss += __shfl_xor(ss, 1); ss += __shfl_xor(ss, 2); ss += __shfl_xor(ss, 4);
  ss += __shfl_xor(ss, 8); ss += __shfl_xor(ss, 16); ss += __shfl_xor(ss, 32);
  float rn = rsqrtf(ss * (1.0f / 128.0f) + 1.1920929e-07f);
  float n0 = x0 * rn, n1 = x1 * rn;
  float partner = __shfl_xor(n0, 16);
  if (lane < 32) {
    int i = lane & 15;
    float c = ctab[s * 16 + i], sn = stab[s * 16 + i];
    n0 = (lane < 16) ? (n0 * c + partner * sn) : (n0 * c - partner * sn);
  }
  if (isQ) { float g = qgain[hh]; n0 *= g; n1 *= g; }
  dst[lane] = f2h_bits(n0);
  dst[lane + 64] = f2h_bits(n1);
}

// ---------------- V transpose: qkv v-block -> Vt[b][kvh][d][s] ----------------
__global__ __launch_bounds__(256) void vtrans(const unsigned short* __restrict__ qkv,
                                              unsigned short* __restrict__ Vt) {
  int idx = blockIdx.x * 256 + threadIdx.x;
  int d = idx & 127;
  int sc = (idx >> 7) & 255;
  int kvh = (idx >> 15) & 3;
  int b = idx >> 17;
  u16x8 v;
#pragma unroll
  for (int j = 0; j < 8; ++j)
    v[j] = qkv[((long)(b * S_LEN + sc * 8 + j)) * 3072 + 2560 + kvh * HD + d];
  *reinterpret_cast<u16x8*>(Vt + (((long)(b * NKV + kvh)) * HD + d) * S_LEN + sc * 8) = v;
}

// ======== causal GQA attention: 256 uniform blocks, 8 waves, counted-vmcnt pipeline ========
// Block (p,h,b): q-blocks p (low) and 15-p (high). Wave w: 16 low rows + 16 high rows.
// K tile [32 rho][128], rho = MFMA A-row (kv permuted at staging), chunk ^= (rho&7).
// V tile [128 d][32 kv], chunk ^= ((d>>1)&3). 4 slots, stage 2 ahead, vmcnt never 0 mid-loop.
#define ATT_C3 ((float)(0.08838834764831845 * (2.0 / 30.0) * 1.4426950408889634))
#define ATT_C4 ((float)(30.0 * 1.4426950408889634))
#define ATT_C5 ((float)(60.0 * 1.4426950408889634))
#define ATT_THR ((float)(8.0 * 1.4426950408889634))

__global__ __launch_bounds__(512, 2) void attn(const unsigned short* __restrict__ Qb,
                                               const unsigned short* __restrict__ Kb,
                                               const unsigned short* __restrict__ Vt,
                                               unsigned short* __restrict__ Yb) {
  __shared__ unsigned short Klds[4][32 * 128];
  __shared__ unsigned short Vlds[4][128 * 32];
  const int tid = threadIdx.x, wid = tid >> 6, lane = tid & 63;
  const int p = blockIdx.x, h = blockIdx.y, b = blockIdx.z;
  const int kvh = h >> 2;
  const int rlo = lane & 15, hi = lane >> 4;
  const int qA0 = p * 128 + wid * 16;
  const int qB0 = (15 - p) * 128 + wid * 16;
  const unsigned short* Kp = Kb + ((long)(b * NKV + kvh)) * S_LEN * HD;
  const unsigned short* Vp = Vt + ((long)(b * NKV + kvh)) * HD * S_LEN;
  const unsigned short* QpA = Qb + (((long)(b * NH + h)) * S_LEN + qA0) * HD;
  const unsigned short* QpB = Qb + (((long)(b * NH + h)) * S_LEN + qB0) * HD;
  f16x8 bqA[4], bqB[4];
#pragma unroll
  for (int dk = 0; dk < 4; ++dk) {
    bqA[dk] = ld8(QpA + rlo * HD + dk * 32 + hi * 8);
    bqB[dk] = ld8(QpB + rlo * HD + dk * 32 + hi * 8);
  }
  // per-thread staging constants (dest linear; kv-permutation + swizzle folded into source)
  const int kRho = tid >> 4;
  const int kvperm = 8 * ((kRho >> 2) & 3) + (kRho & 3) + 4 * (kRho >> 4);
  const int kSrcCh = (tid & 15) ^ (kRho & 7);
  const int kDst = kRho * 128 + (tid & 15) * 8;
  const int vD = tid >> 2;
  const int vSrcCh = (tid & 3) ^ ((vD >> 1) & 3);
  const int vDst = vD * 32 + (tid & 3) * 8;
  const int kx = rlo & 7;
  const int vx = (rlo >> 1) & 3;

  f32x4 accA[8] = {}, accB[8] = {};
  float m2cA = ATT_C4 + 128.0f, m2cB = ATT_C4 + 128.0f;
  float lA = 0.0f, lB = 0.0f;
  const int nt = 4 * (15 - p) + 4;
  const int tAlast = 4 * p + (wid >> 1);
  const int tBlast = 4 * (15 - p) + (wid >> 1);

  auto stage = [&](int slot, int k0) {
    gload_lds16(Kp + (long)(k0 + kvperm) * HD + kSrcCh * 8, &Klds[slot][kDst]);
    gload_lds16(Vp + (long)vD * S_LEN + k0 + vSrcCh * 8, &Vlds[slot][vDst]);
  };

  auto softmax = [&](const f32x4& s0, const f32x4& s1, float& m2c, float& l_run,
                     f32x4* accO, int qrel, bool domask) -> f16x8 {
    float ea[8];
#pragma unroll
    for (int j = 0; j < 8; ++j) {
      float sc = (j < 4) ? s0[j] : s1[j - 4];
      float u = __builtin_amdgcn_exp2f(sc * ATT_C3);
      float rr = __builtin_amdgcn_rcpf(u + 1.0f);
      ea[j] = fmaf(-ATT_C5, rr, m2c);
    }
    if (domask) {
#pragma unroll
      for (int j = 0; j < 8; ++j)
        ea[j] = (8 * hi + j > qrel) ? -1e30f : ea[j];
    }
    float pm = ea[0];
#pragma unroll
    for (int j = 1; j < 8; ++j) pm = fmaxf(pm, ea[j]);
    if (!__all(pm <= ATT_THR)) {
      float red = fmaxf(pm, __shfl_xor(pm, 16));
      red = fmaxf(red, __shfl_xor(red, 32));
      red = fmaxf(red, 0.0f);
      m2c -= red;
      float f = __builtin_amdgcn_exp2f(-red);
      l_run *= f;
#pragma unroll
      for (int dt = 0; dt < 8; ++dt) accO[dt] *= f;
#pragma unroll
      for (int j = 0; j < 8; ++j) ea[j] -= red;
    }
    float pv[8];
#pragma unroll
    for (int j = 0; j < 8; ++j) pv[j] = __builtin_amdgcn_exp2f(ea[j]);
    l_run += ((pv[0] + pv[1]) + (pv[2] + pv[3])) + ((pv[4] + pv[5]) + (pv[6] + pv[7]));
    u32x4 pk;
    pk.x = __builtin_bit_cast(unsigned int, __builtin_amdgcn_cvt_pkrtz(pv[0], pv[1]));
    pk.y = __builtin_bit_cast(unsigned int, __builtin_amdgcn_cvt_pkrtz(pv[2], pv[3]));
    pk.z = __builtin_bit_cast(unsigned int, __builtin_amdgcn_cvt_pkrtz(pv[4], pv[5]));
    pk.w = __builtin_bit_cast(unsigned int, __builtin_amdgcn_cvt_pkrtz(pv[6], pv[7]));
    return __builtin_bit_cast(f16x8, pk);
  };

  // prologue: 2 tiles in flight
  stage(0, 0);
  stage(1, 32);
  for (int t = 0; t < nt; ++t) {
    if (t + 2 < nt) {
      stage((t + 2) & 3, (t + 2) * 32);
      VMWAIT(4);             // tile t's loads (FIFO: t, t+1, t+2 in flight = 6)
    } else if (t + 1 < nt) {
      VMWAIT(2);             // t, t+1 in flight
    } else {
      VMWAIT(0);
    }
    __builtin_amdgcn_s_barrier();
    asm volatile("" ::: "memory");
    if (t <= tBlast) {       // wave-uniform; doA => doB since tAlast < tBlast
      const bool doA = (t <= tAlast);
      const unsigned short* Kt = Klds[t & 3];
      const unsigned short* Vl = Vlds[t & 3];
      // K fragments (shared by A and B)
      f16x8 ka0[4], ka1[4];
#pragma unroll
      for (int dk = 0; dk < 4; ++dk) {
        int cp = ((dk * 4 + hi) ^ kx) * 8;
        ka0[dk] = ld8(&Kt[rlo * 128 + cp]);
        ka1[dk] = ld8(&Kt[(16 + rlo) * 128 + cp]);
      }
      f32x4 s0B = {0.f, 0.f, 0.f, 0.f}, s1B = s0B, s0A = s0B, s1A = s0B;
      __builtin_amdgcn_s_setprio(1);
#pragma unroll
      for (int dk = 0; dk < 4; ++dk) {
        s0B = __builtin_amdgcn_mfma_f32_16x16x32_f16(ka0[dk], bqB[dk], s0B, 0, 0, 0);
        s1B = __builtin_amdgcn_mfma_f32_16x16x32_f16(ka1[dk], bqB[dk], s1B, 0, 0, 0);
      }
      if (doA) {
#pragma unroll
        for (int dk = 0; dk < 4; ++dk) {
          s0A = __builtin_amdgcn_mfma_f32_16x16x32_f16(ka0[dk], bqA[dk], s0A, 0, 0, 0);
          s1A = __builtin_amdgcn_mfma_f32_16x16x32_f16(ka1[dk], bqA[dk], s1A, 0, 0, 0);
        }
      }
      __builtin_amdgcn_s_setprio(0);
      f16x8 bpB = softmax(s0B, s1B, m2cB, lB, accB, qB0 + rlo - 32 * t, t == tBlast);
      f16x8 bpA;
      if (doA) bpA = softmax(s0A, s1A, m2cA, lA, accA, qA0 + rlo - 32 * t, t == tAlast);
      // PV (V frags shared), two groups of 4 to bound VGPR
      __builtin_amdgcn_s_setprio(1);
#pragma unroll
      for (int g = 0; g < 2; ++g) {
        f16x8 av[4];
#pragma unroll
        for (int i = 0; i < 4; ++i) {
          int d = (g * 4 + i) * 16 + rlo;
          av[i] = ld8(&Vl[d * 32 + ((hi ^ vx) * 8)]);
        }
#pragma unroll
        for (int i = 0; i < 4; ++i)
          accB[g * 4 + i] = __builtin_amdgcn_mfma_f32_16x16x32_f16(av[i], bpB, accB[g * 4 + i], 0, 0, 0);
        if (doA) {
#pragma unroll
          for (int i = 0; i < 4; ++i)
            accA[g * 4 + i] = __builtin_amdgcn_mfma_f32_16x16x32_f16(av[i], bpA, accA[g * 4 + i], 0, 0, 0);
        }
      }
      __builtin_amdgcn_s_setprio(0);
    }
  }
  // finalize: combine l across the 4 hi-lanes sharing each q
  float l1 = lA + __shfl_xor(lA, 16); l1 += __shfl_xor(l1, 32);
  float l2 = lB + __shfl_xor(lB, 16); l2 += __shfl_xor(l2, 32);
  float invA2 = 1.0f / l1, invB2 = 1.0f / l2;
  unsigned short* ypA = Yb + ((long)(b * S_LEN + qA0 + rlo)) * DIM + h * HD + 4 * hi;
  unsigned short* ypB = Yb + ((long)(b * S_LEN + qB0 + rlo)) * DIM + h * HD + 4 * hi;
#pragma unroll
  for (int dt = 0; dt < 8; ++dt) {
    u16x4 oA, oB;
#pragma unroll
    for (int r = 0; r < 4; ++r) {
      oA[r] = f2h_bits(accA[dt][r] * invA2);
      oB[r] = f2h_bits(accB[dt][r] * invB2);
    }
    *reinterpret_cast<u16x4*>(ypA + dt * 16) = oA;
    *reinterpret_cast<u16x4*>(ypB + dt * 16) = oB;
  }
}

extern "C" void kernel_launch(void* const* d_in, const int* in_sizes, int n_in,
                              void* d_out, int out_size, void* d_ws, size_t ws_size,
                              hipStream_t stream) {
  const float* x = (const float*)d_in[0];
  const float* Wq = (const float*)d_in[1];
  const float* Wk = (const float*)d_in[2];
  const float* Wv = (const float*)d_in[3];
  const float* Wp = (const float*)d_in[4];
  const float* qg = (const float*)d_in[5];
  float* out = (float*)d_out;

  char* ws = (char*)d_ws;
  size_t off = 0;
  auto alloc = [&](size_t bytes) {
    char* p = ws + off;
    off += (bytes + 255) & ~(size_t)255;
    return p;
  };
  unsigned short* xb   = (unsigned short*)alloc(8388608ull * 2);
  unsigned short* wqkv = (unsigned short*)alloc(6291456ull * 2);
  unsigned short* wpj  = (unsigned short*)alloc(4194304ull * 2);
  unsigned short* qkv  = (unsigned short*)alloc(4096ull * 3072 * 2);
  unsigned short* Qb   = (unsigned short*)alloc(8388608ull * 2);
  unsigned short* Kb   = (unsigned short*)alloc(2097152ull * 2);
  unsigned short* Vt   = (unsigned short*)alloc(2097152ull * 2);
  unsigned short* Yb   = (unsigned short*)alloc(8388608ull * 2);
  float* ctab = (float*)alloc(32768ull * 4);
  float* stab = (float*)alloc(32768ull * 4);

  auto cvt = [&](const float* src, unsigned short* dst, int n) {
    int n4 = n / 4;
    cvt_f32_f16<<<(n4 + 255) / 256, 256, 0, stream>>>(src, dst, n4);
  };
  cvt(x, xb, 8388608);
  cvt(Wq, wqkv, 4194304);
  cvt(Wk, wqkv + 4194304, 1048576);
  cvt(Wv, wqkv + 5242880, 1048576);
  cvt(Wp, wpj, 4194304);
  rope_tables<<<128, 256, 0, stream>>>(ctab, stab);

  gemm8p<4, unsigned short><<<dim3(16, 12), 512, 0, stream>>>(xb, wqkv, qkv, 2048, 3072);

  qknorm_rope<<<(BATCH * S_LEN * (NH + NKV)) / 4, 256, 0, stream>>>(qkv, ctab, stab, qg, Qb, Kb);
  vtrans<<<(BATCH * NKV * HD * (S_LEN / 8)) / 256, 256, 0, stream>>>(qkv, Vt);

  attn<<<dim3(8, NH, BATCH), 512, 0, stream>>>(Qb, Kb, Vt, Yb);

  gemm8p<2, float><<<dim3(16, 16), 512, 0, stream>>>(Yb, wpj, out, 2048, 2048);
}

// Round 7
// 216.330 us; speedup vs baseline: 3.0004x; 1.1237x over previous
//
#include <hip/hip_runtime.h>
#include <type_traits>

#define BATCH 2
#define S_LEN 2048
#define DIM 2048
#define NH 16
#define NKV 4
#define HD 128

typedef _Float16 f16x8 __attribute__((ext_vector_type(8)));
typedef float f32x4 __attribute__((ext_vector_type(4)));
typedef unsigned int u32x4 __attribute__((ext_vector_type(4)));
typedef unsigned short u16x4 __attribute__((ext_vector_type(4)));
typedef unsigned short u16x8 __attribute__((ext_vector_type(8)));

__device__ __forceinline__ unsigned short f2h_bits(float f) {
  _Float16 h = (_Float16)f;
  return __builtin_bit_cast(unsigned short, h);
}
__device__ __forceinline__ float h2f(unsigned short u) {
  return (float)__builtin_bit_cast(_Float16, u);
}
__device__ __forceinline__ f16x8 ld8(const unsigned short* p) {
  u32x4 v = *reinterpret_cast<const u32x4*>(p);
  return __builtin_bit_cast(f16x8, v);
}
__device__ __forceinline__ void gload_lds16(const unsigned short* g, unsigned short* l) {
  __builtin_amdgcn_global_load_lds(
      (const __attribute__((address_space(1))) unsigned int*)g,
      (__attribute__((address_space(3))) unsigned int*)l, 16, 0, 0);
}

#define VMWAIT(n) asm volatile("s_waitcnt vmcnt(" #n ")" ::: "memory")

// ---------------- fp32 -> fp16 convert ----------------
__global__ __launch_bounds__(256) void cvt_f32_f16(const float* __restrict__ in,
                                                   unsigned short* __restrict__ out, int n4) {
  int i = blockIdx.x * 256 + threadIdx.x;
  if (i >= n4) return;
  f32x4 v = *reinterpret_cast<const f32x4*>(in + (long)i * 4);
  u16x4 o;
  o.x = f2h_bits(v.x); o.y = f2h_bits(v.y); o.z = f2h_bits(v.z); o.w = f2h_bits(v.w);
  *reinterpret_cast<u16x4*>(out + (long)i * 4) = o;
}

// ---------------- RoPE tables (fp32) ----------------
__global__ __launch_bounds__(256) void rope_tables(float* __restrict__ c, float* __restrict__ s) {
  int idx = blockIdx.x * 256 + threadIdx.x;
  if (idx >= S_LEN * 16) return;
  int i = idx & 15, t = idx >> 4;
  float inv = exp2f(-(float)i * (13.287712379549449f / 16.0f));
  float f = (float)t * inv;
  c[idx] = cosf(f);
  s[idx] = sinf(f);
}

// ======== pipelined 256-row GEMM: 1 barrier/K-tile, stage-all-ahead, read-ahead regs ========
// BM=256, BN=64*NREP, BK=64. 512 thr = 8 waves (2M x 4N). Per-wave out 128 x 16*NREP.
// LDS slot: A[kk][sig 0..255][32] (sig quarter-permuted; sig&3 == row&3), B[kk][r][32];
// chunk swizzle c = hi ^ (row&3). All 8 stage-loads of tile t+1 issued at tile-t start
// (issue-to-use = full K-tile >> HBM latency, so per-tile vmcnt(0) is pre-satisfied).
// Inside tile: no barriers; MFMA cluster p interleaves with ds_reads for cluster p+1.
template <int NREP, typename OUT>
__global__ __launch_bounds__(512, 2) void gemm_pl(const unsigned short* __restrict__ A,
                                                  const unsigned short* __restrict__ B,
                                                  OUT* __restrict__ C, int K, int ldc) {
  constexpr int BN = 64 * NREP;
  constexpr int BSH = BN * 32;          // shorts per B kk-block
  constexpr int TS = 16384 + 2 * BSH;   // shorts per slot
  __shared__ unsigned short lds[2][TS];
  const int tid = threadIdx.x, lane = tid & 63;
  const int wm = tid >> 8, wn = (tid >> 6) & 3;
  const int rlo = lane & 15, hi = lane >> 4;
  const int m0 = blockIdx.x * 256, n0 = blockIdx.y * BN;
  const int NT = K >> 6;
  const int brow = wn * (16 * NREP);
  const int sA_s = tid >> 2;
  const int pc2 = tid & 3;

  auto aRow = [&](int sig) { return (sig & 63) + ((sig >> 6) & 1) * 128 + (sig >> 7) * 64; };

  // 8 (NREP=3) / 6 (NREP=2) gload_lds per thread, wave-uniform count
  auto stageAll = [&](int slot, int k0) {
#pragma unroll
    for (int kk = 0; kk < 2; ++kk)
#pragma unroll
      for (int sh = 0; sh < 2; ++sh) {
        int sig = sh * 128 + sA_s;
        int r = aRow(sig);
        int lc2 = pc2 ^ (sig & 3);
        gload_lds16(A + (long)(m0 + r) * K + k0 + kk * 32 + lc2 * 8,
                    &lds[slot][kk * 8192 + sh * 4096 + tid * 8]);
      }
#pragma unroll
    for (int kk = 0; kk < 2; ++kk)
#pragma unroll
      for (int q = 0; q < (NREP + 1) / 2; ++q) {
        // q==1 (NREP=3): rows 128..191; waves 4-7 duplicate waves 0-3 (same src+dst,
        // benign, keeps per-wave vmcnt counts uniform)
        int idx = (q == 0) ? tid : (512 + (tid & 255));
        int r = idx >> 2;
        int lc2 = (idx & 3) ^ (r & 3);
        gload_lds16(B + (long)(n0 + r) * K + k0 + kk * 32 + lc2 * 8,
                    &lds[slot][16384 + kk * BSH + idx * 8]);
      }
  };

  f32x4 acc[8][NREP] = {};

  auto rdA = [&](const unsigned short* As, int kk, int mh, f16x8* af) {
#pragma unroll
    for (int i = 0; i < 4; ++i) {
      int ms = mh * 4 + i;
      int sig = (ms & 3) * 16 + rlo + wm * 64 + (ms >> 2) * 128;
      af[i] = ld8(&As[kk * 8192 + sig * 32 + ((hi ^ (sig & 3)) * 8)]);
    }
  };
  auto rdB = [&](const unsigned short* Bs, int kk, f16x8* bf) {
#pragma unroll
    for (int j = 0; j < NREP; ++j) {
      int r = brow + j * 16 + rlo;
      bf[j] = ld8(&Bs[kk * BSH + r * 32 + ((hi ^ (r & 3)) * 8)]);
    }
  };
  auto mm = [&](const f16x8* af, const f16x8* bf, int mh) {
    __builtin_amdgcn_s_setprio(1);
#pragma unroll
    for (int i = 0; i < 4; ++i)
#pragma unroll
      for (int j = 0; j < NREP; ++j)
        acc[mh * 4 + i][j] =
            __builtin_amdgcn_mfma_f32_16x16x32_f16(af[i], bf[j], acc[mh * 4 + i][j], 0, 0, 0);
    __builtin_amdgcn_s_setprio(0);
  };

  stageAll(0, 0);
  for (int t = 0; t < NT; ++t) {
    const int slot = t & 1;
    const unsigned short* As = &lds[slot][0];
    const unsigned short* Bs = &lds[slot][16384];
    VMWAIT(0);                      // tile t's loads: issued one full K-tile ago
    __builtin_amdgcn_s_barrier();   // all waves done reading slot^1 (WAR) + data visible (RAW)
    asm volatile("" ::: "memory");
    if (t + 1 < NT) stageAll(slot ^ 1, (t + 1) << 6);
    f16x8 bf0[NREP], bf1[NREP], afE[4], afO[4];
    rdB(Bs, 0, bf0);
    rdA(As, 0, 0, afE);   // cluster 0 operands first (minimal lgkm wait)
    rdB(Bs, 1, bf1);
    rdA(As, 1, 0, afO);   // cluster 1
    mm(afE, bf0, 0);      // ms0-3 x kk0   (overlaps with reads below)
    rdA(As, 0, 1, afE);   // cluster 2 operands
    mm(afO, bf1, 0);      // ms0-3 x kk1
    rdA(As, 1, 1, afO);   // cluster 3 operands
    mm(afE, bf0, 1);      // ms4-7 x kk0
    mm(afO, bf1, 1);      // ms4-7 x kk1
  }

  // epilogue
#pragma unroll
  for (int ms = 0; ms < 8; ++ms)
#pragma unroll
    for (int j = 0; j < NREP; ++j) {
      int row = m0 + wm * 128 + ms * 16 + hi * 4;
      int col = n0 + brow + j * 16 + rlo;
#pragma unroll
      for (int r = 0; r < 4; ++r) {
        float v = acc[ms][j][r];
        if constexpr (std::is_same<OUT, float>::value)
          C[(long)(row + r) * ldc + col] = v;
        else
          C[(long)(row + r) * ldc + col] = f2h_bits(v);
      }
    }
}

// ---------------- RMSNorm + RoPE + gain, scatter into Q/K layouts ----------------
__global__ __launch_bounds__(256) void qknorm_rope(const unsigned short* __restrict__ qkv,
                                                   const float* __restrict__ ctab,
                                                   const float* __restrict__ stab,
                                                   const float* __restrict__ qgain,
                                                   unsigned short* __restrict__ Qb,
                                                   unsigned short* __restrict__ Kb) {
  const int lane = threadIdx.x & 63;
  const int row = blockIdx.x * 4 + (threadIdx.x >> 6);
  const int NQROWS = BATCH * S_LEN * NH;
  const unsigned short* src;
  unsigned short* dst;
  int m, hh;
  bool isQ;
  if (row < NQROWS) {
    m = row >> 4; hh = row & 15;
    src = qkv + (long)m * 3072 + hh * HD;
    int b = m >> 11, s = m & (S_LEN - 1);
    dst = Qb + (((long)(b * NH + hh)) * S_LEN + s) * HD;
    isQ = true;
  } else {
    int rk = row - NQROWS;
    m = rk >> 2; hh = rk & 3;
    src = qkv + (long)m * 3072 + 2048 + hh * HD;
    int b = m >> 11, s = m & (S_LEN - 1);
    dst = Kb + (((long)(b * NKV + hh)) * S_LEN + s) * HD;
    isQ = false;
  }
  const int s = m & (S_LEN - 1);
  float x0 = h2f(src[lane]);
  float x1 = h2f(src[lane + 64]);
  float ss = x0 * x0 + x1 * x1;
  ss += __shfl_xor(ss, 1); ss += __shfl_xor(ss, 2); ss += __shfl_xor(ss, 4);
  ss += __shfl_xor(ss, 8); ss += __shfl_xor(ss, 16); ss += __shfl_xor(ss, 32);
  float rn = rsqrtf(ss * (1.0f / 128.0f) + 1.1920929e-07f);
  float n0 = x0 * rn, n1 = x1 * rn;
  float partner = __shfl_xor(n0, 16);
  if (lane < 32) {
    int i = lane & 15;
    float c = ctab[s * 16 + i], sn = stab[s * 16 + i];
    n0 = (lane < 16) ? (n0 * c + partner * sn) : (n0 * c - partner * sn);
  }
  if (isQ) { float g = qgain[hh]; n0 *= g; n1 *= g; }
  dst[lane] = f2h_bits(n0);
  dst[lane + 64] = f2h_bits(n1);
}

// ---------------- V transpose: qkv v-block -> Vt[b][kvh][d][s] ----------------
__global__ __launch_bounds__(256) void vtrans(const unsigned short* __restrict__ qkv,
                                              unsigned short* __restrict__ Vt) {
  int idx = blockIdx.x * 256 + threadIdx.x;
  int d = idx & 127;
  int sc = (idx >> 7) & 255;
  int kvh = (idx >> 15) & 3;
  int b = idx >> 17;
  u16x8 v;
#pragma unroll
  for (int j = 0; j < 8; ++j)
    v[j] = qkv[((long)(b * S_LEN + sc * 8 + j)) * 3072 + 2560 + kvh * HD + d];
  *reinterpret_cast<u16x8*>(Vt + (((long)(b * NKV + kvh)) * HD + d) * S_LEN + sc * 8) = v;
}

// ======== causal GQA attention (unchanged from round 6) ========
#define ATT_C3 ((float)(0.08838834764831845 * (2.0 / 30.0) * 1.4426950408889634))
#define ATT_C4 ((float)(30.0 * 1.4426950408889634))
#define ATT_C5 ((float)(60.0 * 1.4426950408889634))
#define ATT_THR ((float)(8.0 * 1.4426950408889634))

__global__ __launch_bounds__(512, 2) void attn(const unsigned short* __restrict__ Qb,
                                               const unsigned short* __restrict__ Kb,
                                               const unsigned short* __restrict__ Vt,
                                               unsigned short* __restrict__ Yb) {
  __shared__ unsigned short Klds[4][32 * 128];
  __shared__ unsigned short Vlds[4][128 * 32];
  const int tid = threadIdx.x, wid = tid >> 6, lane = tid & 63;
  const int p = blockIdx.x, h = blockIdx.y, b = blockIdx.z;
  const int kvh = h >> 2;
  const int rlo = lane & 15, hi = lane >> 4;
  const int qA0 = p * 128 + wid * 16;
  const int qB0 = (15 - p) * 128 + wid * 16;
  const unsigned short* Kp = Kb + ((long)(b * NKV + kvh)) * S_LEN * HD;
  const unsigned short* Vp = Vt + ((long)(b * NKV + kvh)) * HD * S_LEN;
  const unsigned short* QpA = Qb + (((long)(b * NH + h)) * S_LEN + qA0) * HD;
  const unsigned short* QpB = Qb + (((long)(b * NH + h)) * S_LEN + qB0) * HD;
  f16x8 bqA[4], bqB[4];
#pragma unroll
  for (int dk = 0; dk < 4; ++dk) {
    bqA[dk] = ld8(QpA + rlo * HD + dk * 32 + hi * 8);
    bqB[dk] = ld8(QpB + rlo * HD + dk * 32 + hi * 8);
  }
  const int kRho = tid >> 4;
  const int kvperm = 8 * ((kRho >> 2) & 3) + (kRho & 3) + 4 * (kRho >> 4);
  const int kSrcCh = (tid & 15) ^ (kRho & 7);
  const int kDst = kRho * 128 + (tid & 15) * 8;
  const int vD = tid >> 2;
  const int vSrcCh = (tid & 3) ^ ((vD >> 1) & 3);
  const int vDst = vD * 32 + (tid & 3) * 8;
  const int kx = rlo & 7;
  const int vx = (rlo >> 1) & 3;

  f32x4 accA[8] = {}, accB[8] = {};
  float m2cA = ATT_C4 + 128.0f, m2cB = ATT_C4 + 128.0f;
  float lA = 0.0f, lB = 0.0f;
  const int nt = 4 * (15 - p) + 4;
  const int tAlast = 4 * p + (wid >> 1);
  const int tBlast = 4 * (15 - p) + (wid >> 1);

  auto stage = [&](int slot, int k0) {
    gload_lds16(Kp + (long)(k0 + kvperm) * HD + kSrcCh * 8, &Klds[slot][kDst]);
    gload_lds16(Vp + (long)vD * S_LEN + k0 + vSrcCh * 8, &Vlds[slot][vDst]);
  };

  auto softmax = [&](const f32x4& s0, const f32x4& s1, float& m2c, float& l_run,
                     f32x4* accO, int qrel, bool domask) -> f16x8 {
    float ea[8];
#pragma unroll
    for (int j = 0; j < 8; ++j) {
      float sc = (j < 4) ? s0[j] : s1[j - 4];
      float u = __builtin_amdgcn_exp2f(sc * ATT_C3);
      float rr = __builtin_amdgcn_rcpf(u + 1.0f);
      ea[j] = fmaf(-ATT_C5, rr, m2c);
    }
    if (domask) {
#pragma unroll
      for (int j = 0; j < 8; ++j)
        ea[j] = (8 * hi + j > qrel) ? -1e30f : ea[j];
    }
    float pm = ea[0];
#pragma unroll
    for (int j = 1; j < 8; ++j) pm = fmaxf(pm, ea[j]);
    if (!__all(pm <= ATT_THR)) {
      float red = fmaxf(pm, __shfl_xor(pm, 16));
      red = fmaxf(red, __shfl_xor(red, 32));
      red = fmaxf(red, 0.0f);
      m2c -= red;
      float f = __builtin_amdgcn_exp2f(-red);
      l_run *= f;
#pragma unroll
      for (int dt = 0; dt < 8; ++dt) accO[dt] *= f;
#pragma unroll
      for (int j = 0; j < 8; ++j) ea[j] -= red;
    }
    float pv[8];
#pragma unroll
    for (int j = 0; j < 8; ++j) pv[j] = __builtin_amdgcn_exp2f(ea[j]);
    l_run += ((pv[0] + pv[1]) + (pv[2] + pv[3])) + ((pv[4] + pv[5]) + (pv[6] + pv[7]));
    u32x4 pk;
    pk.x = __builtin_bit_cast(unsigned int, __builtin_amdgcn_cvt_pkrtz(pv[0], pv[1]));
    pk.y = __builtin_bit_cast(unsigned int, __builtin_amdgcn_cvt_pkrtz(pv[2], pv[3]));
    pk.z = __builtin_bit_cast(unsigned int, __builtin_amdgcn_cvt_pkrtz(pv[4], pv[5]));
    pk.w = __builtin_bit_cast(unsigned int, __builtin_amdgcn_cvt_pkrtz(pv[6], pv[7]));
    return __builtin_bit_cast(f16x8, pk);
  };

  stage(0, 0);
  stage(1, 32);
  for (int t = 0; t < nt; ++t) {
    if (t + 2 < nt) {
      stage((t + 2) & 3, (t + 2) * 32);
      VMWAIT(4);
    } else if (t + 1 < nt) {
      VMWAIT(2);
    } else {
      VMWAIT(0);
    }
    __builtin_amdgcn_s_barrier();
    asm volatile("" ::: "memory");
    if (t <= tBlast) {
      const bool doA = (t <= tAlast);
      const unsigned short* Kt = Klds[t & 3];
      const unsigned short* Vl = Vlds[t & 3];
      f16x8 ka0[4], ka1[4];
#pragma unroll
      for (int dk = 0; dk < 4; ++dk) {
        int cp = ((dk * 4 + hi) ^ kx) * 8;
        ka0[dk] = ld8(&Kt[rlo * 128 + cp]);
        ka1[dk] = ld8(&Kt[(16 + rlo) * 128 + cp]);
      }
      f32x4 s0B = {0.f, 0.f, 0.f, 0.f}, s1B = s0B, s0A = s0B, s1A = s0B;
      __builtin_amdgcn_s_setprio(1);
#pragma unroll
      for (int dk = 0; dk < 4; ++dk) {
        s0B = __builtin_amdgcn_mfma_f32_16x16x32_f16(ka0[dk], bqB[dk], s0B, 0, 0, 0);
        s1B = __builtin_amdgcn_mfma_f32_16x16x32_f16(ka1[dk], bqB[dk], s1B, 0, 0, 0);
      }
      if (doA) {
#pragma unroll
        for (int dk = 0; dk < 4; ++dk) {
          s0A = __builtin_amdgcn_mfma_f32_16x16x32_f16(ka0[dk], bqA[dk], s0A, 0, 0, 0);
          s1A = __builtin_amdgcn_mfma_f32_16x16x32_f16(ka1[dk], bqA[dk], s1A, 0, 0, 0);
        }
      }
      __builtin_amdgcn_s_setprio(0);
      f16x8 bpB = softmax(s0B, s1B, m2cB, lB, accB, qB0 + rlo - 32 * t, t == tBlast);
      f16x8 bpA;
      if (doA) bpA = softmax(s0A, s1A, m2cA, lA, accA, qA0 + rlo - 32 * t, t == tAlast);
      __builtin_amdgcn_s_setprio(1);
#pragma unroll
      for (int g = 0; g < 2; ++g) {
        f16x8 av[4];
#pragma unroll
        for (int i = 0; i < 4; ++i) {
          int d = (g * 4 + i) * 16 + rlo;
          av[i] = ld8(&Vl[d * 32 + ((hi ^ vx) * 8)]);
        }
#pragma unroll
        for (int i = 0; i < 4; ++i)
          accB[g * 4 + i] = __builtin_amdgcn_mfma_f32_16x16x32_f16(av[i], bpB, accB[g * 4 + i], 0, 0, 0);
        if (doA) {
#pragma unroll
          for (int i = 0; i < 4; ++i)
            accA[g * 4 + i] = __builtin_amdgcn_mfma_f32_16x16x32_f16(av[i], bpA, accA[g * 4 + i], 0, 0, 0);
        }
      }
      __builtin_amdgcn_s_setprio(0);
    }
  }
  float l1 = lA + __shfl_xor(lA, 16); l1 += __shfl_xor(l1, 32);
  float l2 = lB + __shfl_xor(lB, 16); l2 += __shfl_xor(l2, 32);
  float invA2 = 1.0f / l1, invB2 = 1.0f / l2;
  unsigned short* ypA = Yb + ((long)(b * S_LEN + qA0 + rlo)) * DIM + h * HD + 4 * hi;
  unsigned short* ypB = Yb + ((long)(b * S_LEN + qB0 + rlo)) * DIM + h * HD + 4 * hi;
#pragma unroll
  for (int dt = 0; dt < 8; ++dt) {
    u16x4 oA, oB;
#pragma unroll
    for (int r = 0; r < 4; ++r) {
      oA[r] = f2h_bits(accA[dt][r] * invA2);
      oB[r] = f2h_bits(accB[dt][r] * invB2);
    }
    *reinterpret_cast<u16x4*>(ypA + dt * 16) = oA;
    *reinterpret_cast<u16x4*>(ypB + dt * 16) = oB;
  }
}

extern "C" void kernel_launch(void* const* d_in, const int* in_sizes, int n_in,
                              void* d_out, int out_size, void* d_ws, size_t ws_size,
                              hipStream_t stream) {
  const float* x = (const float*)d_in[0];
  const float* Wq = (const float*)d_in[1];
  const float* Wk = (const float*)d_in[2];
  const float* Wv = (const float*)d_in[3];
  const float* Wp = (const float*)d_in[4];
  const float* qg = (const float*)d_in[5];
  float* out = (float*)d_out;

  char* ws = (char*)d_ws;
  size_t off = 0;
  auto alloc = [&](size_t bytes) {
    char* p = ws + off;
    off += (bytes + 255) & ~(size_t)255;
    return p;
  };
  unsigned short* xb   = (unsigned short*)alloc(8388608ull * 2);
  unsigned short* wqkv = (unsigned short*)alloc(6291456ull * 2);
  unsigned short* wpj  = (unsigned short*)alloc(4194304ull * 2);
  unsigned short* qkv  = (unsigned short*)alloc(4096ull * 3072 * 2);
  unsigned short* Qb   = (unsigned short*)alloc(8388608ull * 2);
  unsigned short* Kb   = (unsigned short*)alloc(2097152ull * 2);
  unsigned short* Vt   = (unsigned short*)alloc(2097152ull * 2);
  unsigned short* Yb   = (unsigned short*)alloc(8388608ull * 2);
  float* ctab = (float*)alloc(32768ull * 4);
  float* stab = (float*)alloc(32768ull * 4);

  auto cvt = [&](const float* src, unsigned short* dst, int n) {
    int n4 = n / 4;
    cvt_f32_f16<<<(n4 + 255) / 256, 256, 0, stream>>>(src, dst, n4);
  };
  cvt(x, xb, 8388608);
  cvt(Wq, wqkv, 4194304);
  cvt(Wk, wqkv + 4194304, 1048576);
  cvt(Wv, wqkv + 5242880, 1048576);
  cvt(Wp, wpj, 4194304);
  rope_tables<<<128, 256, 0, stream>>>(ctab, stab);

  // qkv = x @ [Wq;Wk;Wv]^T : M=4096 N=3072 K=2048  (256x192 tiles -> 256 blocks)
  gemm_pl<3, unsigned short><<<dim3(16, 16), 512, 0, stream>>>(xb, wqkv, qkv, 2048, 3072);

  qknorm_rope<<<(BATCH * S_LEN * (NH + NKV)) / 4, 256, 0, stream>>>(qkv, ctab, stab, qg, Qb, Kb);
  vtrans<<<(BATCH * NKV * HD * (S_LEN / 8)) / 256, 256, 0, stream>>>(qkv, Vt);

  attn<<<dim3(8, NH, BATCH), 512, 0, stream>>>(Qb, Kb, Vt, Yb);

  // out = y @ Wproj^T : M=4096 N=2048 K=2048  (256x128 tiles -> 256 blocks)
  gemm_pl<2, float><<<dim3(16, 16), 512, 0, stream>>>(Yb, wpj, out, 2048, 2048);
}